// Round 2
// baseline (1116.159 us; speedup 1.0000x reference)
//
#include <hip/hip_runtime.h>
#include <hip/hip_bf16.h>

typedef __attribute__((ext_vector_type(4))) float f32x4;
typedef __attribute__((ext_vector_type(8))) short bf16x8;
typedef __attribute__((ext_vector_type(4))) short s16x4;

#define LCOUNT 6

static __device__ __forceinline__ unsigned short f2b(float f){
  __hip_bfloat16 h = __float2bfloat16(f);
  return __builtin_bit_cast(unsigned short, h);
}
static __device__ __forceinline__ float b2f(unsigned short u){
  unsigned int x = ((unsigned int)u) << 16;
  return __builtin_bit_cast(float, x);
}
static __device__ __forceinline__ void gl16(const void* g, void* l){
  __builtin_amdgcn_global_load_lds(
      (const __attribute__((address_space(1))) void*)g,
      (__attribute__((address_space(3))) void*)l, 16, 0, 0);
}
static __device__ __forceinline__ f32x4 mfma16(bf16x8 a, bf16x8 b, f32x4 c){
  return __builtin_amdgcn_mfma_f32_16x16x32_bf16(a, b, c, 0, 0, 0);
}

// ---------------- setup kernels ----------------
__global__ void k_cvt(const float* __restrict__ s, unsigned short* __restrict__ d, int n){
  int i = blockIdx.x*256 + threadIdx.x;
  if (i < n) d[i] = f2b(s[i]);
}

// dist f32 [32][1000][1000] -> bf16 [32][1000][1024] (k-pad zeros)
__global__ void k_cvtdist(const float* __restrict__ dist, unsigned short* __restrict__ db){
  int t = blockIdx.x*256 + threadIdx.x;   // 32000*128 = 4,096,000
  int row = t >> 7, ch = t & 127;
  bf16x8 w;
  if (ch >= 125){
#pragma unroll
    for (int e=0;e<8;e++) w[e] = 0;
  } else {
    const float* p = dist + (size_t)row*1000 + ch*8;
    f32x4 a = *(const f32x4*)p;
    f32x4 b = *(const f32x4*)(p + 4);
#pragma unroll
    for (int e=0;e<4;e++){ w[e] = (short)f2b(a[e]); w[4+e] = (short)f2b(b[e]); }
  }
  *(bf16x8*)&db[(size_t)row*1024 + ch*8] = w;
}

__global__ void k_embed(const float* __restrict__ data, const float* __restrict__ We,
                        const float* __restrict__ be, float* __restrict__ x,
                        unsigned short* __restrict__ xb){
  int idx = blockIdx.x*256 + threadIdx.x;   // 4,096,000
  int d = idx & 127, bn = idx >> 7;
  float v = data[bn*2]*We[d*2] + data[bn*2+1]*We[d*2+1] + be[d];
  x[idx] = v; xb[idx] = f2b(v);
}

// ---------------- InstanceNorm helpers ----------------
__global__ void k_stats(const float* __restrict__ x, float* __restrict__ part){
  int d = threadIdx.x, c = blockIdx.x, b = blockIdx.y;
  float s1 = 0.f, s2 = 0.f;
  int n0 = c*125;
  for (int n = n0; n < n0+125; ++n){
    float v = x[((size_t)b*1000 + n)*128 + d];
    s1 += v; s2 += v*v;
  }
  int o = ((b*8 + c)*128 + d)*2;
  part[o] = s1; part[o+1] = s2;
}

__global__ void k_fin(const float* __restrict__ part, const float* __restrict__ g,
                      const float* __restrict__ bta, float* __restrict__ na,
                      float* __restrict__ nc){
  int t = blockIdx.x*128 + threadIdx.x;  // 4096
  int b = t >> 7, d = t & 127;
  float s1 = 0.f, s2 = 0.f;
  for (int c = 0; c < 8; ++c){
    int o = ((b*8 + c)*128 + d)*2;
    s1 += part[o]; s2 += part[o+1];
  }
  float mean = s1 * 1e-3f;
  float var  = s2 * 1e-3f - mean*mean;
  float inv  = rsqrtf(var + 1e-5f);
  float a = g[d] * inv;
  na[t] = a; nc[t] = bta[d] - mean*a;
}

__global__ void k_apply(const float* __restrict__ src, const float* __restrict__ na,
                        const float* __restrict__ nc, float* __restrict__ dstf,
                        unsigned short* __restrict__ dstb, float* __restrict__ dout){
  int idx = blockIdx.x*256 + threadIdx.x;
  int d = idx & 127; int bn = idx >> 7; int b = bn/1000;
  int t = b*128 + d;
  float v = src[idx]*na[t] + nc[t];
  dstf[idx] = v; dstb[idx] = f2b(v);
  if (dout) dout[idx] = v;
}

// ---------------- unified weight GEMM ----------------
// MODE 0: Q   -> sigmoid -> sigq bf16 [32000][128]
// MODE 1: KV  -> paired k,v accs; ek & ek*v transposed into Zt [b][256][1024]
// MODE 2: FF1 -> bias+relu -> h1 bf16 [32000][512] (blockIdx.y = 128-col chunk)
// MODE 3: FF2 -> bias + addsrc -> f32 out [32000][128]
template<int MODE>
__global__ __launch_bounds__(256) void gemm_w(
  const unsigned short* __restrict__ A,
  const unsigned short* __restrict__ B0,
  const unsigned short* __restrict__ B1,
  const float* __restrict__ bias,
  float* __restrict__ outf,
  unsigned short* __restrict__ outb,
  const float* __restrict__ addsrc)
{
  constexpr int K  = (MODE==3) ? 512 : 128;
  constexpr int NK = K/32;
  constexpr int BR = (MODE==1) ? 256 : 128;
  __shared__ unsigned short LA[2][4][128][8];
  __shared__ unsigned short LB[2][4][BR][8];
  int tid = threadIdx.x, wid = tid>>6, lane = tid&63;
  int l15 = lane&15, lg = lane>>4;
  int wm = wid>>1, wn = wid&1;
  int m0 = blockIdx.x * 128;
  const unsigned short* Bp = B0;
  int col0 = 0;
  if constexpr (MODE==2){ col0 = blockIdx.y*128; Bp = B0 + (size_t)col0*K; }

  f32x4 zf = {0.f,0.f,0.f,0.f};
  f32x4 acc[4][4], acc2[4][4];
#pragma unroll
  for (int i=0;i<4;i++)
#pragma unroll
    for (int j=0;j<4;j++){ acc[i][j] = zf; acc2[i][j] = zf; }

  auto stage = [&](int kk, int buf){
    int k0 = kk*32;
#pragma unroll
    for (int t2=0;t2<2;++t2){
      int e = wid + t2*4;
      int g = e>>1, rb = e&1;
      gl16(A + (size_t)(m0 + rb*64 + lane)*K + k0 + g*8, &LA[buf][g][rb*64][0]);
    }
#pragma unroll
    for (int t2=0;t2<BR/64;++t2){
      int e = wid + t2*4;
      int g, rb;
      if constexpr (BR==256){ g = e&3; rb = e>>2; } else { g = e>>1; rb = e&1; }
      const unsigned short* src;
      if constexpr (MODE==1)
        src = (rb < 2) ? (B0 + (size_t)(rb*64 + lane)*K + k0 + g*8)
                       : (B1 + (size_t)((rb-2)*64 + lane)*K + k0 + g*8);
      else
        src = Bp + (size_t)(rb*64 + lane)*K + k0 + g*8;
      gl16(src, &LB[buf][g][rb*64][0]);
    }
  };

  auto compute = [&](int buf){
    bf16x8 af[4], bq[4];
#pragma unroll
    for (int i=0;i<4;i++) af[i] = *(const bf16x8*)&LA[buf][lg][wm*64 + i*16 + l15][0];
#pragma unroll
    for (int j=0;j<4;j++) bq[j] = *(const bf16x8*)&LB[buf][lg][wn*64 + j*16 + l15][0];
#pragma unroll
    for (int i=0;i<4;i++)
#pragma unroll
      for (int j=0;j<4;j++)
        acc[i][j] = mfma16(af[i], bq[j], acc[i][j]);
    if constexpr (MODE==1){
      bf16x8 bv[4];
#pragma unroll
      for (int j=0;j<4;j++) bv[j] = *(const bf16x8*)&LB[buf][lg][128 + wn*64 + j*16 + l15][0];
#pragma unroll
      for (int i=0;i<4;i++)
#pragma unroll
        for (int j=0;j<4;j++)
          acc2[i][j] = mfma16(af[i], bv[j], acc2[i][j]);
    }
  };

  stage(0, 0);
  __syncthreads();
  for (int kk = 0; kk < NK; ++kk){
    int buf = kk & 1;
    if (kk + 1 < NK) stage(kk+1, buf^1);
    compute(buf);
    __syncthreads();
  }

  int rbase = lg*4;
#pragma unroll
  for (int i=0;i<4;i++){
    int row0 = m0 + wm*64 + i*16 + rbase;
#pragma unroll
    for (int j=0;j<4;j++){
      int col = col0 + wn*64 + j*16 + l15;
      if constexpr (MODE==0){
#pragma unroll
        for (int r=0;r<4;r++)
          outb[(size_t)(row0+r)*128 + col] = f2b(1.f/(1.f + __expf(-acc[i][j][r])));
      } else if constexpr (MODE==1){
        unsigned short uk[4], uv[4];
#pragma unroll
        for (int r=0;r<4;r++){
          float ek = __expf(acc[i][j][r]);
          uk[r] = f2b(ek);
          uv[r] = f2b(ek * acc2[i][j][r]);
        }
        int b0i = row0/1000, n0r = row0 - b0i*1000;
        if (n0r <= 996){
          s16x4 pv = {(short)uv[0],(short)uv[1],(short)uv[2],(short)uv[3]};
          s16x4 pk = {(short)uk[0],(short)uk[1],(short)uk[2],(short)uk[3]};
          *(s16x4*)&outb[((size_t)b0i*256 + col)*1024 + n0r] = pv;
          *(s16x4*)&outb[((size_t)b0i*256 + 128 + col)*1024 + n0r] = pk;
        } else {
#pragma unroll
          for (int r=0;r<4;r++){
            int gr = row0 + r; int bb2 = gr/1000, nn = gr - bb2*1000;
            outb[((size_t)bb2*256 + col)*1024 + nn] = uv[r];
            outb[((size_t)bb2*256 + 128 + col)*1024 + nn] = uk[r];
          }
        }
      } else if constexpr (MODE==2){
        float bz = bias[col];
#pragma unroll
        for (int r=0;r<4;r++){
          float v = acc[i][j][r] + bz;
          outb[(size_t)(row0+r)*512 + col] = f2b(v > 0.f ? v : 0.f);
        }
      } else {
        float bz = bias[col];
#pragma unroll
        for (int r=0;r<4;r++){
          size_t idx = (size_t)(row0+r)*128 + col;
          outf[idx] = acc[i][j][r] + bz + addsrc[idx];
        }
      }
    }
  }
}

// ---------------- fused attention: BD = exp(sc*dist) @ [ekv|ek]; x += sig*b/d ----------------
// BM=64 rows(n), BN=256 cols, BK=32 over m (1024 padded), 4 waves, 512 blocks
template<int USE16>
__global__ __launch_bounds__(256) void attn_fused(
  const float* __restrict__ dist, const unsigned short* __restrict__ db16,
  const unsigned short* __restrict__ Zt,
  const unsigned short* __restrict__ sigq, float* __restrict__ x,
  const float* __restrict__ log_scale, const float* __restrict__ alpha, int layer)
{
  union SM {
    struct { unsigned short A[2][4][64][8]; unsigned short B[2][4][256][8]; } st;
    float den[64][128];
  };
  __shared__ SM sm;
  int tid = threadIdx.x, wid = tid>>6, lane = tid&63;
  int l15 = lane&15, lg = lane>>4;
  int bb = blockIdx.y, n0 = blockIdx.x*64;
  float sc = log_scale[0]*alpha[layer];
  const unsigned short* Zb = Zt + ((size_t)bb << 18);
  int arow = tid>>2, ag = tid&3;
  int an = n0 + arow; if (an > 999) an = 999;
  const size_t drow = (size_t)(bb*1000 + an);

  f32x4 zf = {0.f,0.f,0.f,0.f};
  f32x4 acc[4][4];
#pragma unroll
  for (int i=0;i<4;i++)
#pragma unroll
    for (int j=0;j<4;j++) acc[i][j] = zf;

  auto issueB = [&](int kk, int buf){
    int k0 = kk*32;
#pragma unroll
    for (int t2=0;t2<4;++t2){
      int e = wid + t2*4;
      int g = e&3, cb = e>>2;
      gl16(Zb + (size_t)(cb*64 + lane)*1024 + k0 + g*8, &sm.st.B[buf][g][cb*64][0]);
    }
  };
  auto loadA = [&](int kk, float* v){
    int k0 = kk*32 + ag*8;
    if (USE16){
      bf16x8 r = *(const bf16x8*)(db16 + drow*1024 + k0);
#pragma unroll
      for (int e=0;e<8;e++) v[e] = b2f((unsigned short)r[e]);
    } else {
      const float* dp = dist + drow*1000;
      if (k0 + 8 <= 1000){
        f32x4 a0 = *(const f32x4*)(dp + k0);
        f32x4 a1 = *(const f32x4*)(dp + k0 + 4);
#pragma unroll
        for (int e=0;e<4;e++){ v[e] = a0[e]; v[4+e] = a1[e]; }
      } else {
#pragma unroll
        for (int e=0;e<8;e++){
          int m = k0 + e; if (m > 999) m = 999;
          v[e] = dp[m];
        }
      }
    }
  };
  auto expwrite = [&](const float* v, int buf){
    bf16x8 w;
#pragma unroll
    for (int e=0;e<8;e++) w[e] = (short)f2b(__expf(sc*v[e]));
    *(bf16x8*)&sm.st.A[buf][ag][arow][0] = w;
  };
  auto compute = [&](int buf){
    bf16x8 af[4], bq[4];
#pragma unroll
    for (int i=0;i<4;i++) af[i] = *(const bf16x8*)&sm.st.A[buf][lg][i*16 + l15][0];
#pragma unroll
    for (int j=0;j<4;j++) bq[j] = *(const bf16x8*)&sm.st.B[buf][lg][wid*64 + j*16 + l15][0];
#pragma unroll
    for (int i=0;i<4;i++)
#pragma unroll
      for (int j=0;j<4;j++)
        acc[i][j] = mfma16(af[i], bq[j], acc[i][j]);
  };

  float av[8];
  issueB(0, 0);
  loadA(0, av);
  expwrite(av, 0);
  __syncthreads();
  for (int kk = 0; kk < 32; ++kk){
    int buf = kk & 1;
    float nv[8];
    if (kk < 31){ issueB(kk+1, buf^1); loadA(kk+1, nv); }
    compute(buf);
    if (kk < 31) expwrite(nv, buf^1);
    __syncthreads();
  }

  int rbase = lg*4;
  if (wid >= 2){
#pragma unroll
    for (int i=0;i<4;i++)
#pragma unroll
      for (int j=0;j<4;j++){
        int dcol = (wid-2)*64 + j*16 + l15;
#pragma unroll
        for (int r=0;r<4;r++)
          sm.den[i*16 + rbase + r][dcol] = acc[i][j][r];
      }
  }
  __syncthreads();
  if (wid < 2){
#pragma unroll
    for (int i=0;i<4;i++){
#pragma unroll
      for (int r=0;r<4;r++){
        int n = n0 + i*16 + rbase + r;
        if (n < 1000){
          size_t rowi = ((size_t)bb*1000 + n)*128;
#pragma unroll
          for (int j=0;j<4;j++){
            int d = wid*64 + j*16 + l15;
            float den = sm.den[i*16 + rbase + r][d];
            float sg = b2f(sigq[rowi + d]);
            x[rowi + d] += sg * acc[i][j][r] / den;
          }
        }
      }
    }
  }
}

extern "C" void kernel_launch(void* const* d_in, const int* in_sizes, int n_in,
                              void* d_out, int out_size, void* d_ws, size_t ws_size,
                              hipStream_t stream) {
  const float* data = (const float*)d_in[0];
  const float* dist = (const float*)d_in[1];
  const float* log_scale = (const float*)d_in[2];
  const float* We = (const float*)d_in[3];
  const float* be = (const float*)d_in[4];
  const float* Wq = (const float*)d_in[5];
  const float* Wk = (const float*)d_in[6];
  const float* Wv = (const float*)d_in[7];
  const float* g1 = (const float*)d_in[8];
  const float* b1 = (const float*)d_in[9];
  const float* W1 = (const float*)d_in[10];
  const float* bw1 = (const float*)d_in[11];
  const float* W2 = (const float*)d_in[12];
  const float* bw2 = (const float*)d_in[13];
  const float* g2 = (const float*)d_in[14];
  const float* b2 = (const float*)d_in[15];
  const float* alpha = (const float*)d_in[16];
  float* dout = (float*)d_out;

  char* ws = (char*)d_ws;
  size_t off = 0;
  auto alloc = [&](size_t bytes) -> void* {
    void* p = ws + off; off += (bytes + 255) & ~(size_t)255; return p;
  };
  unsigned short* xb  = (unsigned short*)alloc(8192000);    // [32000][128] bf16
  float* x            = (float*)alloc(16384000);            // [32000][128] f32
  unsigned short* sigq= (unsigned short*)alloc(8192000);    // [32000][128] bf16
  unsigned short* Zt  = (unsigned short*)alloc(16777216);   // [32][256][1024] bf16
  unsigned short* h1  = (unsigned short*)alloc(32768000);   // [32000][512] bf16
  float* x1           = (float*)alloc(16384000);
  unsigned short* x1b = (unsigned short*)alloc(8192000);
  float* part         = (float*)alloc(262144);
  float* na           = (float*)alloc(16384);
  float* nc           = (float*)alloc(16384);
  unsigned short* wqb = (unsigned short*)alloc(196608);
  unsigned short* wkb = (unsigned short*)alloc(196608);
  unsigned short* wvb = (unsigned short*)alloc(196608);
  unsigned short* w1b = (unsigned short*)alloc(786432);
  unsigned short* w2b = (unsigned short*)alloc(786432);
  if (off > ws_size) return;
  unsigned short* db16p = nullptr;
  if (ws_size >= off + 65536256) db16p = (unsigned short*)alloc(65536000); // [32000][1024] bf16

  hipMemsetAsync(Zt, 0, 16777216, stream);
  k_cvt<<<384, 256, 0, stream>>>(Wq, wqb, 98304);
  k_cvt<<<384, 256, 0, stream>>>(Wk, wkb, 98304);
  k_cvt<<<384, 256, 0, stream>>>(Wv, wvb, 98304);
  k_cvt<<<1536, 256, 0, stream>>>(W1, w1b, 393216);
  k_cvt<<<1536, 256, 0, stream>>>(W2, w2b, 393216);
  if (db16p) k_cvtdist<<<16000, 256, 0, stream>>>(dist, db16p);
  k_embed<<<16000, 256, 0, stream>>>(data, We, be, x, xb);

  for (int i = 0; i < LCOUNT; ++i){
    gemm_w<0><<<250, 256, 0, stream>>>(xb, wqb + i*16384, nullptr, nullptr,
                                       nullptr, sigq, nullptr);
    gemm_w<1><<<250, 256, 0, stream>>>(xb, wkb + i*16384, wvb + i*16384, nullptr,
                                       nullptr, Zt, nullptr);
    if (db16p)
      attn_fused<1><<<dim3(16,32), 256, 0, stream>>>(dist, db16p, Zt, sigq, x,
                                                     log_scale, alpha, i);
    else
      attn_fused<0><<<dim3(16,32), 256, 0, stream>>>(dist, nullptr, Zt, sigq, x,
                                                     log_scale, alpha, i);
    k_stats<<<dim3(8,32), 128, 0, stream>>>(x, part);
    k_fin<<<32, 128, 0, stream>>>(part, g1 + i*128, b1 + i*128, na, nc);
    k_apply<<<16000, 256, 0, stream>>>(x, na, nc, x1, x1b, nullptr);
    gemm_w<2><<<dim3(250,4), 256, 0, stream>>>(x1b, w1b + i*65536, nullptr,
                                               bw1 + i*512, nullptr, h1, nullptr);
    gemm_w<3><<<250, 256, 0, stream>>>(h1, w2b + i*65536, nullptr,
                                       bw2 + i*128, x, nullptr, x1);
    k_stats<<<dim3(8,32), 128, 0, stream>>>(x, part);
    k_fin<<<32, 128, 0, stream>>>(part, g2 + i*128, b2 + i*128, na, nc);
    k_apply<<<16000, 256, 0, stream>>>(x, na, nc, x, xb,
                                       (i == LCOUNT-1) ? dout : nullptr);
  }
}

// Round 3
// 964.615 us; speedup vs baseline: 1.1571x; 1.1571x over previous
//
#include <hip/hip_runtime.h>
#include <hip/hip_bf16.h>

typedef __attribute__((ext_vector_type(4))) float f32x4;
typedef __attribute__((ext_vector_type(8))) short bf16x8;
typedef __attribute__((ext_vector_type(4))) short s16x4;

#define LCOUNT 6

static __device__ __forceinline__ unsigned short f2b(float f){
  __hip_bfloat16 h = __float2bfloat16(f);
  return __builtin_bit_cast(unsigned short, h);
}
static __device__ __forceinline__ float b2f(unsigned short u){
  unsigned int x = ((unsigned int)u) << 16;
  return __builtin_bit_cast(float, x);
}
static __device__ __forceinline__ void gl16(const void* g, void* l){
  __builtin_amdgcn_global_load_lds(
      (const __attribute__((address_space(1))) void*)g,
      (__attribute__((address_space(3))) void*)l, 16, 0, 0);
}
static __device__ __forceinline__ f32x4 mfma16(bf16x8 a, bf16x8 b, f32x4 c){
  return __builtin_amdgcn_mfma_f32_16x16x32_bf16(a, b, c, 0, 0, 0);
}

// ---------------- setup kernels ----------------
__global__ void k_cvt5(const float* __restrict__ Wq, const float* __restrict__ Wk,
                       const float* __restrict__ Wv, const float* __restrict__ W1,
                       const float* __restrict__ W2,
                       unsigned short* __restrict__ wqb, unsigned short* __restrict__ wkb,
                       unsigned short* __restrict__ wvb, unsigned short* __restrict__ w1b,
                       unsigned short* __restrict__ w2b){
  int i = blockIdx.x*256 + threadIdx.x;  // 1,081,344 total
  if (i < 98304) wqb[i] = f2b(Wq[i]);
  else if (i < 196608) wkb[i-98304] = f2b(Wk[i-98304]);
  else if (i < 294912) wvb[i-196608] = f2b(Wv[i-196608]);
  else if (i < 688128) w1b[i-294912] = f2b(W1[i-294912]);
  else w2b[i-688128] = f2b(W2[i-688128]);
}

// dist f32 [32][1000][1000] -> bf16 [32][1000][1024] (k-pad zeros)
__global__ void k_cvtdist(const float* __restrict__ dist, unsigned short* __restrict__ db){
  int t = blockIdx.x*256 + threadIdx.x;   // 32000*128
  int row = t >> 7, ch = t & 127;
  bf16x8 w;
  if (ch >= 125){
#pragma unroll
    for (int e=0;e<8;e++) w[e] = 0;
  } else {
    const float* p = dist + (size_t)row*1000 + ch*8;
    f32x4 a = *(const f32x4*)p;
    f32x4 b = *(const f32x4*)(p + 4);
#pragma unroll
    for (int e=0;e<4;e++){ w[e] = (short)f2b(a[e]); w[4+e] = (short)f2b(b[e]); }
  }
  *(bf16x8*)&db[(size_t)row*1024 + ch*8] = w;
}

__global__ void k_embed(const float* __restrict__ data, const float* __restrict__ We,
                        const float* __restrict__ be, float* __restrict__ x,
                        unsigned short* __restrict__ xb){
  int idx = blockIdx.x*256 + threadIdx.x;   // 4,096,000
  int d = idx & 127, bn = idx >> 7;
  float v = data[bn*2]*We[d*2] + data[bn*2+1]*We[d*2+1] + be[d];
  x[idx] = v; xb[idx] = f2b(v);
}

// ---------------- fused fin+apply ----------------
// 4000 blocks x 256 thr; block = 8 rows (never straddles batch: 1000%8==0)
__global__ __launch_bounds__(256) void k_napply(
  const float* __restrict__ src, const float* __restrict__ part, int cnt,
  const float* __restrict__ g, const float* __restrict__ beta,
  float* __restrict__ dstf, unsigned short* __restrict__ dstb,
  float* __restrict__ dout)
{
  __shared__ float sna[128], snc[128];
  int blk = blockIdx.x, tid = threadIdx.x;
  int b = blk / 125;
  if (tid < 128){
    float s1 = 0.f, s2 = 0.f;
    for (int c = 0; c < cnt; ++c){
      size_t pi = (((size_t)b*cnt + c)*128 + tid)*2;
      s1 += part[pi]; s2 += part[pi+1];
    }
    float mean = s1 * 1e-3f;
    float var  = s2 * 1e-3f - mean*mean;
    float a = g[tid] * rsqrtf(var + 1e-5f);
    sna[tid] = a; snc[tid] = beta[tid] - mean*a;
  }
  __syncthreads();
  size_t base = (size_t)blk*1024 + tid*4;
  f32x4 v = *(const f32x4*)&src[base];
  int d0 = (tid*4) & 127;
  f32x4 o; s16x4 ob;
#pragma unroll
  for (int e=0;e<4;e++){
    o[e] = v[e]*sna[d0+e] + snc[d0+e];
    ob[e] = (short)f2b(o[e]);
  }
  *(f32x4*)&dstf[base] = o;
  *(s16x4*)&dstb[base] = ob;
  if (dout) *(f32x4*)&dout[base] = o;
}

// ---------------- fused QKV GEMM ----------------
// grid (512, 2): x = b*16 + tile(64 rows), y: 0=Q->sigq, 1=KV->Zc(chunked)
// BM=64, 4 waves (2 row x 2 col), K=128
__global__ __launch_bounds__(256) void k_qkv(
  const unsigned short* __restrict__ xb,
  const unsigned short* __restrict__ Wqb, const unsigned short* __restrict__ Wkb,
  const unsigned short* __restrict__ Wvb,
  unsigned short* __restrict__ sigq, unsigned short* __restrict__ Zc)
{
  __shared__ unsigned short LA[2][4][64][8];
  __shared__ unsigned short LB[2][4][256][8];
  int tid = threadIdx.x, wid = tid>>6, lane = tid&63;
  int l15 = lane&15, lg = lane>>4;
  int wm = wid>>1, wn = wid&1;
  int bt = blockIdx.x, b = bt>>4, t = bt&15;
  int kv = blockIdx.y;
  int lrow = t*64 + lane; if (lrow > 999) lrow = 999;
  size_t arow = (size_t)(b*1000 + lrow);

  f32x4 zf = {0.f,0.f,0.f,0.f};
  f32x4 acc[2][4], acc2[2][4];
#pragma unroll
  for (int i=0;i<2;i++)
#pragma unroll
    for (int j=0;j<4;j++){ acc[i][j] = zf; acc2[i][j] = zf; }

  auto stage = [&](int kk, int buf){
    int k0 = kk*32;
    gl16(xb + arow*128 + k0 + wid*8, &LA[buf][wid][0][0]);
    if (kv == 0){
#pragma unroll
      for (int t2=0;t2<2;++t2){
        int e = wid + t2*4, g2 = e>>1, nb = e&1;
        gl16(Wqb + (size_t)(nb*64+lane)*128 + k0 + g2*8, &LB[buf][g2][nb*64][0]);
      }
    } else {
#pragma unroll
      for (int t2=0;t2<4;++t2){
        int e = wid + t2*4, g2 = e&3, nb = e>>2;
        const unsigned short* src = (nb < 2)
          ? Wkb + (size_t)(nb*64+lane)*128 + k0 + g2*8
          : Wvb + (size_t)((nb-2)*64+lane)*128 + k0 + g2*8;
        gl16(src, &LB[buf][g2][nb*64][0]);
      }
    }
  };
  auto compute = [&](int buf){
    bf16x8 af[2];
#pragma unroll
    for (int i=0;i<2;i++) af[i] = *(const bf16x8*)&LA[buf][lg][wm*32 + i*16 + l15][0];
#pragma unroll
    for (int j=0;j<4;j++){
      bf16x8 bq = *(const bf16x8*)&LB[buf][lg][wn*64 + j*16 + l15][0];
#pragma unroll
      for (int i=0;i<2;i++) acc[i][j] = mfma16(af[i], bq, acc[i][j]);
      if (kv){
        bf16x8 bv = *(const bf16x8*)&LB[buf][lg][128 + wn*64 + j*16 + l15][0];
#pragma unroll
        for (int i=0;i<2;i++) acc2[i][j] = mfma16(af[i], bv, acc2[i][j]);
      }
    }
  };

  stage(0, 0);
  __syncthreads();
  for (int kk = 0; kk < 4; ++kk){
    int buf = kk & 1;
    if (kk < 3) stage(kk+1, buf^1);
    compute(buf);
    __syncthreads();
  }

#pragma unroll
  for (int i=0;i<2;i++){
    int m4 = t*64 + wm*32 + i*16 + lg*4;
    if (m4 >= 1000) continue;
#pragma unroll
    for (int j=0;j<4;j++){
      int col = wn*64 + j*16 + l15;
      if (kv == 0){
#pragma unroll
        for (int r=0;r<4;r++)
          sigq[(size_t)(b*1000 + m4 + r)*128 + col] = f2b(1.f/(1.f + __expf(-acc[i][j][r])));
      } else {
        s16x4 pv, pk;
#pragma unroll
        for (int r=0;r<4;r++){
          float ek = __expf(acc[i][j][r]);
          pk[r] = (short)f2b(ek);
          pv[r] = (short)f2b(ek * acc2[i][j][r]);
        }
        size_t base = ((size_t)(b*128 + (m4>>3))*256 + col)*8 + ((m4>>2)&1)*4;
        *(s16x4*)&Zc[base] = pv;          // ekv at col
        *(s16x4*)&Zc[base + 1024] = pk;   // ek  at col+128
      }
    }
  }
}

// ---------------- fused attention + stats ----------------
// grid (16,32): 64 n-rows x 256 cols, K=1024 (chunked Zc), 4 waves
template<int USE16>
__global__ __launch_bounds__(256) void k_attn(
  const float* __restrict__ dist, const unsigned short* __restrict__ db16,
  const unsigned short* __restrict__ Zc, const unsigned short* __restrict__ sigq,
  float* __restrict__ x, float* __restrict__ partA,
  const float* __restrict__ log_scale, const float* __restrict__ alpha, int layer)
{
  union SM {
    struct { unsigned short A[2][4][64][8]; unsigned short B[2][4][256][8]; } st;
    float den[64][128];
  };
  __shared__ SM sm;
  int tid = threadIdx.x, wid = tid>>6, lane = tid&63;
  int l15 = lane&15, lg = lane>>4;
  int bb = blockIdx.y, t = blockIdx.x, n0 = t*64;
  float sc = log_scale[0]*alpha[layer];
  const unsigned short* Zb = Zc + ((size_t)bb << 18);
  int arow = tid>>2, ag = tid&3;
  int an = n0 + arow; if (an > 999) an = 999;
  const size_t drow = (size_t)(bb*1000 + an);

  f32x4 zf = {0.f,0.f,0.f,0.f};
  f32x4 acc[4][4];
#pragma unroll
  for (int i=0;i<4;i++)
#pragma unroll
    for (int j=0;j<4;j++) acc[i][j] = zf;

  auto issueB = [&](int kk, int buf){
#pragma unroll
    for (int t2=0;t2<4;++t2){
      int e = wid + t2*4, g2 = e&3, cb = e>>2;
      gl16(Zb + ((size_t)((kk*4 + g2)*256 + cb*64 + lane))*8, &sm.st.B[buf][g2][cb*64][0]);
    }
  };
  auto loadA = [&](int kk, float* v){
    int k0 = kk*32 + ag*8;
    if (USE16){
      bf16x8 r = *(const bf16x8*)(db16 + drow*1024 + k0);
#pragma unroll
      for (int e=0;e<8;e++) v[e] = b2f((unsigned short)r[e]);
    } else {
      const float* dp = dist + (size_t)drow*1000;
      if (k0 + 8 <= 1000){
        f32x4 a0 = *(const f32x4*)(dp + k0);
        f32x4 a1 = *(const f32x4*)(dp + k0 + 4);
#pragma unroll
        for (int e=0;e<4;e++){ v[e] = a0[e]; v[4+e] = a1[e]; }
      } else {
#pragma unroll
        for (int e=0;e<8;e++){
          int m = k0 + e; if (m > 999) m = 999;
          v[e] = dp[m];
        }
      }
    }
  };
  auto expwrite = [&](const float* v, int buf){
    bf16x8 w;
#pragma unroll
    for (int e=0;e<8;e++) w[e] = (short)f2b(__expf(sc*v[e]));
    *(bf16x8*)&sm.st.A[buf][ag][arow][0] = w;
  };
  auto compute = [&](int buf){
    bf16x8 af[4], bq[4];
#pragma unroll
    for (int i=0;i<4;i++) af[i] = *(const bf16x8*)&sm.st.A[buf][lg][i*16 + l15][0];
#pragma unroll
    for (int j=0;j<4;j++) bq[j] = *(const bf16x8*)&sm.st.B[buf][lg][wid*64 + j*16 + l15][0];
#pragma unroll
    for (int i=0;i<4;i++)
#pragma unroll
      for (int j=0;j<4;j++)
        acc[i][j] = mfma16(af[i], bq[j], acc[i][j]);
  };

  float av[8];
  issueB(0, 0);
  loadA(0, av);
  expwrite(av, 0);
  __syncthreads();
  for (int kk = 0; kk < 32; ++kk){
    int buf = kk & 1;
    float nv[8];
    if (kk < 31){ issueB(kk+1, buf^1); loadA(kk+1, nv); }
    compute(buf);
    if (kk < 31) expwrite(nv, buf^1);
    __syncthreads();
  }

  if (wid >= 2){
#pragma unroll
    for (int i=0;i<4;i++)
#pragma unroll
      for (int j=0;j<4;j++){
        int dcol = (wid-2)*64 + j*16 + l15;
#pragma unroll
        for (int r=0;r<4;r++)
          sm.den[i*16 + lg*4 + r][dcol] = acc[i][j][r];
      }
  }
  __syncthreads();
  if (wid < 2){
    float s1[4] = {0.f,0.f,0.f,0.f}, s2[4] = {0.f,0.f,0.f,0.f};
#pragma unroll
    for (int i=0;i<4;i++){
#pragma unroll
      for (int r=0;r<4;r++){
        int n = n0 + i*16 + lg*4 + r;
        if (n < 1000){
          size_t rowi = ((size_t)bb*1000 + n)*128;
#pragma unroll
          for (int j=0;j<4;j++){
            int d = wid*64 + j*16 + l15;
            float y = x[rowi + d] +
                      b2f(sigq[rowi + d]) * acc[i][j][r] / sm.den[i*16 + lg*4 + r][d];
            x[rowi + d] = y;
            s1[j] += y; s2[j] += y*y;
          }
        }
      }
    }
#pragma unroll
    for (int j=0;j<4;j++){
      s1[j] += __shfl_xor(s1[j], 16); s2[j] += __shfl_xor(s2[j], 16);
      s1[j] += __shfl_xor(s1[j], 32); s2[j] += __shfl_xor(s2[j], 32);
    }
    if (lg == 0){
#pragma unroll
      for (int j=0;j<4;j++){
        int d = wid*64 + j*16 + l15;
        size_t pi = (((size_t)bb*16 + t)*128 + d)*2;
        partA[pi] = s1[j]; partA[pi+1] = s2[j];
      }
    }
  }
}

// ---------------- FF1: x1b @ W1^T + bias, relu -> h1 bf16 ----------------
// grid (500, 4): 64 rows x 128-col chunk, K=128
__global__ __launch_bounds__(256) void k_ff1(
  const unsigned short* __restrict__ x1b, const unsigned short* __restrict__ W1b,
  const float* __restrict__ bw1, unsigned short* __restrict__ h1)
{
  __shared__ unsigned short LA[2][4][64][8];
  __shared__ unsigned short LB[2][4][128][8];
  int tid = threadIdx.x, wid = tid>>6, lane = tid&63;
  int l15 = lane&15, lg = lane>>4;
  int wm = wid>>1, wn = wid&1;
  int m0 = blockIdx.x*64, col0 = blockIdx.y*128;

  f32x4 zf = {0.f,0.f,0.f,0.f};
  f32x4 acc[2][4];
#pragma unroll
  for (int i=0;i<2;i++)
#pragma unroll
    for (int j=0;j<4;j++) acc[i][j] = zf;

  auto stage = [&](int kk, int buf){
    int k0 = kk*32;
    gl16(x1b + (size_t)(m0 + lane)*128 + k0 + wid*8, &LA[buf][wid][0][0]);
#pragma unroll
    for (int t2=0;t2<2;++t2){
      int e = wid + t2*4, g2 = e>>1, nb = e&1;
      gl16(W1b + (size_t)(col0 + nb*64 + lane)*128 + k0 + g2*8, &LB[buf][g2][nb*64][0]);
    }
  };
  auto compute = [&](int buf){
    bf16x8 af[2];
#pragma unroll
    for (int i=0;i<2;i++) af[i] = *(const bf16x8*)&LA[buf][lg][wm*32 + i*16 + l15][0];
#pragma unroll
    for (int j=0;j<4;j++){
      bf16x8 bq = *(const bf16x8*)&LB[buf][lg][wn*64 + j*16 + l15][0];
#pragma unroll
      for (int i=0;i<2;i++) acc[i][j] = mfma16(af[i], bq, acc[i][j]);
    }
  };

  stage(0, 0);
  __syncthreads();
  for (int kk = 0; kk < 4; ++kk){
    int buf = kk & 1;
    if (kk < 3) stage(kk+1, buf^1);
    compute(buf);
    __syncthreads();
  }

#pragma unroll
  for (int i=0;i<2;i++){
    int row0 = m0 + wm*32 + i*16 + lg*4;
#pragma unroll
    for (int j=0;j<4;j++){
      int col = col0 + wn*64 + j*16 + l15;
      float bz = bw1[col];
#pragma unroll
      for (int r=0;r<4;r++){
        float v = acc[i][j][r] + bz;
        h1[(size_t)(row0+r)*512 + col] = f2b(v > 0.f ? v : 0.f);
      }
    }
  }
}

// ---------------- FF2 + residual + stats: h1 @ W2^T + bias + x1 -> x, partF ----------------
// grid 512 (per-batch 64-row tiles), K=512
__global__ __launch_bounds__(256) void k_ff2(
  const unsigned short* __restrict__ h1, const unsigned short* __restrict__ W2b,
  const float* __restrict__ bw2, const float* __restrict__ x1,
  float* __restrict__ x, float* __restrict__ partF)
{
  __shared__ unsigned short LA[2][4][64][8];
  __shared__ unsigned short LB[2][4][128][8];
  int tid = threadIdx.x, wid = tid>>6, lane = tid&63;
  int l15 = lane&15, lg = lane>>4;
  int wm = wid>>1, wn = wid&1;
  int bt = blockIdx.x, b = bt>>4, t = bt&15;
  int lrow = t*64 + lane; if (lrow > 999) lrow = 999;
  size_t arow = (size_t)(b*1000 + lrow);

  f32x4 zf = {0.f,0.f,0.f,0.f};
  f32x4 acc[2][4];
#pragma unroll
  for (int i=0;i<2;i++)
#pragma unroll
    for (int j=0;j<4;j++) acc[i][j] = zf;

  auto stage = [&](int kk, int buf){
    int k0 = kk*32;
    gl16(h1 + arow*512 + k0 + wid*8, &LA[buf][wid][0][0]);
#pragma unroll
    for (int t2=0;t2<2;++t2){
      int e = wid + t2*4, g2 = e>>1, nb = e&1;
      gl16(W2b + (size_t)(nb*64 + lane)*512 + k0 + g2*8, &LB[buf][g2][nb*64][0]);
    }
  };
  auto compute = [&](int buf){
    bf16x8 af[2];
#pragma unroll
    for (int i=0;i<2;i++) af[i] = *(const bf16x8*)&LA[buf][lg][wm*32 + i*16 + l15][0];
#pragma unroll
    for (int j=0;j<4;j++){
      bf16x8 bq = *(const bf16x8*)&LB[buf][lg][wn*64 + j*16 + l15][0];
#pragma unroll
      for (int i=0;i<2;i++) acc[i][j] = mfma16(af[i], bq, acc[i][j]);
    }
  };

  stage(0, 0);
  __syncthreads();
  for (int kk = 0; kk < 16; ++kk){
    int buf = kk & 1;
    if (kk < 15) stage(kk+1, buf^1);
    compute(buf);
    __syncthreads();
  }

  float s1[4] = {0.f,0.f,0.f,0.f}, s2[4] = {0.f,0.f,0.f,0.f};
#pragma unroll
  for (int i=0;i<2;i++){
    int m4 = t*64 + wm*32 + i*16 + lg*4;
    if (m4 >= 1000) continue;
#pragma unroll
    for (int j=0;j<4;j++){
      int col = wn*64 + j*16 + l15;
      float bz = bw2[col];
#pragma unroll
      for (int r=0;r<4;r++){
        size_t idx = (size_t)(b*1000 + m4 + r)*128 + col;
        float y = acc[i][j][r] + bz + x1[idx];
        x[idx] = y;
        s1[j] += y; s2[j] += y*y;
      }
    }
  }
#pragma unroll
  for (int j=0;j<4;j++){
    s1[j] += __shfl_xor(s1[j], 16); s2[j] += __shfl_xor(s2[j], 16);
    s1[j] += __shfl_xor(s1[j], 32); s2[j] += __shfl_xor(s2[j], 32);
  }
  if (lg == 0){
#pragma unroll
    for (int j=0;j<4;j++){
      int d = wn*64 + j*16 + l15;
      size_t pi = (((size_t)b*32 + t*2 + wm)*128 + d)*2;
      partF[pi] = s1[j]; partF[pi+1] = s2[j];
    }
  }
}

extern "C" void kernel_launch(void* const* d_in, const int* in_sizes, int n_in,
                              void* d_out, int out_size, void* d_ws, size_t ws_size,
                              hipStream_t stream) {
  const float* data = (const float*)d_in[0];
  const float* dist = (const float*)d_in[1];
  const float* log_scale = (const float*)d_in[2];
  const float* We = (const float*)d_in[3];
  const float* be = (const float*)d_in[4];
  const float* Wq = (const float*)d_in[5];
  const float* Wk = (const float*)d_in[6];
  const float* Wv = (const float*)d_in[7];
  const float* g1 = (const float*)d_in[8];
  const float* b1 = (const float*)d_in[9];
  const float* W1 = (const float*)d_in[10];
  const float* bw1 = (const float*)d_in[11];
  const float* W2 = (const float*)d_in[12];
  const float* bw2 = (const float*)d_in[13];
  const float* g2 = (const float*)d_in[14];
  const float* b2 = (const float*)d_in[15];
  const float* alpha = (const float*)d_in[16];
  float* dout = (float*)d_out;

  char* ws = (char*)d_ws;
  size_t off = 0;
  auto alloc = [&](size_t bytes) -> void* {
    void* p = ws + off; off += (bytes + 255) & ~(size_t)255; return p;
  };
  unsigned short* xb  = (unsigned short*)alloc(8192000);    // [32000][128] bf16
  float* x            = (float*)alloc(16384000);            // [32000][128] f32
  unsigned short* sigq= (unsigned short*)alloc(8192000);    // [32000][128] bf16
  unsigned short* Zc  = (unsigned short*)alloc(16777216);   // [32][128][256][8] bf16
  unsigned short* h1  = (unsigned short*)alloc(32768000);   // [32000][512] bf16
  float* x1           = (float*)alloc(16384000);
  unsigned short* x1b = (unsigned short*)alloc(8192000);
  float* partA        = (float*)alloc(524288);              // [32][16][128][2]
  float* partF        = (float*)alloc(1048576);             // [32][32][128][2]
  unsigned short* wqb = (unsigned short*)alloc(196608);
  unsigned short* wkb = (unsigned short*)alloc(196608);
  unsigned short* wvb = (unsigned short*)alloc(196608);
  unsigned short* w1b = (unsigned short*)alloc(786432);
  unsigned short* w2b = (unsigned short*)alloc(786432);
  if (off > ws_size) return;
  unsigned short* db16p = nullptr;
  if (ws_size >= off + 131072256) db16p = (unsigned short*)alloc(131072000); // [32000][1024] bf16

  hipMemsetAsync(Zc, 0, 16777216, stream);   // m-pad chunks stay zero
  k_cvt5<<<4224, 256, 0, stream>>>(Wq, Wk, Wv, W1, W2, wqb, wkb, wvb, w1b, w2b);
  if (db16p) k_cvtdist<<<16000, 256, 0, stream>>>(dist, db16p);
  k_embed<<<16000, 256, 0, stream>>>(data, We, be, x, xb);

  for (int i = 0; i < LCOUNT; ++i){
    k_qkv<<<dim3(512,2), 256, 0, stream>>>(xb, wqb + i*16384, wkb + i*16384,
                                           wvb + i*16384, sigq, Zc);
    if (db16p)
      k_attn<1><<<dim3(16,32), 256, 0, stream>>>(dist, db16p, Zc, sigq, x, partA,
                                                 log_scale, alpha, i);
    else
      k_attn<0><<<dim3(16,32), 256, 0, stream>>>(dist, nullptr, Zc, sigq, x, partA,
                                                 log_scale, alpha, i);
    k_napply<<<4000, 256, 0, stream>>>(x, partA, 16, g1 + i*128, b1 + i*128,
                                       x1, x1b, nullptr);
    k_ff1<<<dim3(500,4), 256, 0, stream>>>(x1b, w1b + i*65536, bw1 + i*512, h1);
    k_ff2<<<512, 256, 0, stream>>>(h1, w2b + i*65536, bw2 + i*128, x1, x, partF);
    k_napply<<<4000, 256, 0, stream>>>(x, partF, 32, g2 + i*128, b2 + i*128,
                                       x, xb, (i == LCOUNT-1) ? dout : nullptr);
  }
}

// Round 5
// 927.697 us; speedup vs baseline: 1.2032x; 1.0398x over previous
//
#include <hip/hip_runtime.h>
#include <hip/hip_bf16.h>

typedef __attribute__((ext_vector_type(4))) float f32x4;
typedef __attribute__((ext_vector_type(8))) short bf16x8;
typedef __attribute__((ext_vector_type(4))) short s16x4;

#define LCOUNT 6

static __device__ __forceinline__ unsigned short f2b(float f){
  __hip_bfloat16 h = __float2bfloat16(f);
  return __builtin_bit_cast(unsigned short, h);
}
static __device__ __forceinline__ float b2f(unsigned short u){
  unsigned int x = ((unsigned int)u) << 16;
  return __builtin_bit_cast(float, x);
}
static __device__ __forceinline__ void gl16(const void* g, void* l){
  __builtin_amdgcn_global_load_lds(
      (const __attribute__((address_space(1))) void*)g,
      (__attribute__((address_space(3))) void*)l, 16, 0, 0);
}
static __device__ __forceinline__ f32x4 mfma16(bf16x8 a, bf16x8 b, f32x4 c){
  return __builtin_amdgcn_mfma_f32_16x16x32_bf16(a, b, c, 0, 0, 0);
}

// ---------------- setup kernels ----------------
__global__ void k_cvt5(const float* __restrict__ Wq, const float* __restrict__ Wk,
                       const float* __restrict__ Wv, const float* __restrict__ W1,
                       const float* __restrict__ W2,
                       unsigned short* __restrict__ wqb, unsigned short* __restrict__ wkb,
                       unsigned short* __restrict__ wvb, unsigned short* __restrict__ w1b,
                       unsigned short* __restrict__ w2b){
  int i = blockIdx.x*256 + threadIdx.x;  // 1,081,344 total
  if (i < 98304) wqb[i] = f2b(Wq[i]);
  else if (i < 196608) wkb[i-98304] = f2b(Wk[i-98304]);
  else if (i < 294912) wvb[i-196608] = f2b(Wv[i-196608]);
  else if (i < 688128) w1b[i-294912] = f2b(W1[i-294912]);
  else w2b[i-688128] = f2b(W2[i-688128]);
}

// dist f32 [32][1000][1000] -> bf16 [32][1000][1024] (k-pad zeros)
__global__ void k_cvtdist(const float* __restrict__ dist, unsigned short* __restrict__ db){
  int t = blockIdx.x*256 + threadIdx.x;   // 32000*128
  int row = t >> 7, ch = t & 127;
  bf16x8 w;
  if (ch >= 125){
#pragma unroll
    for (int e=0;e<8;e++) w[e] = 0;
  } else {
    const float* p = dist + (size_t)row*1000 + ch*8;
    f32x4 a = *(const f32x4*)p;
    f32x4 b = *(const f32x4*)(p + 4);
#pragma unroll
    for (int e=0;e<4;e++){ w[e] = (short)f2b(a[e]); w[4+e] = (short)f2b(b[e]); }
  }
  *(bf16x8*)&db[(size_t)row*1024 + ch*8] = w;
}

__global__ void k_embed(const float* __restrict__ data, const float* __restrict__ We,
                        const float* __restrict__ be, float* __restrict__ x,
                        unsigned short* __restrict__ xb){
  int idx = blockIdx.x*256 + threadIdx.x;   // 4,096,000
  int d = idx & 127, bn = idx >> 7;
  float v = data[bn*2]*We[d*2] + data[bn*2+1]*We[d*2+1] + be[d];
  x[idx] = v; xb[idx] = f2b(v);
}

// ---------------- fused fin+apply (norm2) ----------------
__global__ __launch_bounds__(256) void k_napply(
  const float* __restrict__ src, const float* __restrict__ part, int cnt,
  const float* __restrict__ g, const float* __restrict__ beta,
  float* __restrict__ dstf, unsigned short* __restrict__ dstb,
  float* __restrict__ dout)
{
  __shared__ float sna[128], snc[128];
  int blk = blockIdx.x, tid = threadIdx.x;
  int b = blk / 125;
  if (tid < 128){
    float s1 = 0.f, s2 = 0.f;
    for (int c = 0; c < cnt; ++c){
      size_t pi = (((size_t)b*cnt + c)*128 + tid)*2;
      s1 += part[pi]; s2 += part[pi+1];
    }
    float mean = s1 * 1e-3f;
    float var  = s2 * 1e-3f - mean*mean;
    float a = g[tid] * rsqrtf(var + 1e-5f);
    sna[tid] = a; snc[tid] = beta[tid] - mean*a;
  }
  __syncthreads();
  size_t base = (size_t)blk*1024 + tid*4;
  f32x4 v = *(const f32x4*)&src[base];
  int d0 = (tid*4) & 127;
  f32x4 o; s16x4 ob;
#pragma unroll
  for (int e=0;e<4;e++){
    o[e] = v[e]*sna[d0+e] + snc[d0+e];
    ob[e] = (short)f2b(o[e]);
  }
  *(f32x4*)&dstf[base] = o;
  *(s16x4*)&dstb[base] = ob;
  if (dout) *(f32x4*)&dout[base] = o;
}

// ---------------- fused QKV GEMM ----------------
// grid (512, 2): x = b*16 + tile(64 rows), y: 0=Q->sigq, 1=KV->Zc(chunked)
__global__ __launch_bounds__(256) void k_qkv(
  const unsigned short* __restrict__ xb,
  const unsigned short* __restrict__ Wqb, const unsigned short* __restrict__ Wkb,
  const unsigned short* __restrict__ Wvb,
  unsigned short* __restrict__ sigq, unsigned short* __restrict__ Zc)
{
  __shared__ unsigned short LA[2][4][64][8];
  __shared__ unsigned short LB[2][4][256][8];
  int tid = threadIdx.x, wid = tid>>6, lane = tid&63;
  int l15 = lane&15, lg = lane>>4;
  int wm = wid>>1, wn = wid&1;
  int bt = blockIdx.x, b = bt>>4, t = bt&15;
  int kv = blockIdx.y;
  int lrow = t*64 + lane; if (lrow > 999) lrow = 999;
  size_t arow = (size_t)(b*1000 + lrow);

  f32x4 zf = {0.f,0.f,0.f,0.f};
  f32x4 acc[2][4], acc2[2][4];
#pragma unroll
  for (int i=0;i<2;i++)
#pragma unroll
    for (int j=0;j<4;j++){ acc[i][j] = zf; acc2[i][j] = zf; }

  auto stage = [&](int kk, int buf){
    int k0 = kk*32;
    gl16(xb + arow*128 + k0 + wid*8, &LA[buf][wid][0][0]);
    if (kv == 0){
#pragma unroll
      for (int t2=0;t2<2;++t2){
        int e = wid + t2*4, g2 = e>>1, nb = e&1;
        gl16(Wqb + (size_t)(nb*64+lane)*128 + k0 + g2*8, &LB[buf][g2][nb*64][0]);
      }
    } else {
#pragma unroll
      for (int t2=0;t2<4;++t2){
        int e = wid + t2*4, g2 = e&3, nb = e>>2;
        const unsigned short* src = (nb < 2)
          ? Wkb + (size_t)(nb*64+lane)*128 + k0 + g2*8
          : Wvb + (size_t)((nb-2)*64+lane)*128 + k0 + g2*8;
        gl16(src, &LB[buf][g2][nb*64][0]);
      }
    }
  };
  auto compute = [&](int buf){
    bf16x8 af[2];
#pragma unroll
    for (int i=0;i<2;i++) af[i] = *(const bf16x8*)&LA[buf][lg][wm*32 + i*16 + l15][0];
#pragma unroll
    for (int j=0;j<4;j++){
      bf16x8 bq = *(const bf16x8*)&LB[buf][lg][wn*64 + j*16 + l15][0];
#pragma unroll
      for (int i=0;i<2;i++) acc[i][j] = mfma16(af[i], bq, acc[i][j]);
      if (kv){
        bf16x8 bv = *(const bf16x8*)&LB[buf][lg][128 + wn*64 + j*16 + l15][0];
#pragma unroll
        for (int i=0;i<2;i++) acc2[i][j] = mfma16(af[i], bv, acc2[i][j]);
      }
    }
  };

  stage(0, 0);
  __syncthreads();
  for (int kk = 0; kk < 4; ++kk){
    int buf = kk & 1;
    if (kk < 3) stage(kk+1, buf^1);
    compute(buf);
    __syncthreads();
  }

#pragma unroll
  for (int i=0;i<2;i++){
    int m4 = t*64 + wm*32 + i*16 + lg*4;
    if (m4 >= 1000) continue;
#pragma unroll
    for (int j=0;j<4;j++){
      int col = wn*64 + j*16 + l15;
      if (kv == 0){
#pragma unroll
        for (int r=0;r<4;r++)
          sigq[(size_t)(b*1000 + m4 + r)*128 + col] = f2b(1.f/(1.f + __expf(-acc[i][j][r])));
      } else {
        s16x4 pv, pk;
#pragma unroll
        for (int r=0;r<4;r++){
          float ek = __expf(acc[i][j][r]);
          pk[r] = (short)f2b(ek);
          pv[r] = (short)f2b(ek * acc2[i][j][r]);
        }
        size_t base = ((size_t)(b*128 + (m4>>3))*256 + col)*8 + ((m4>>2)&1)*4;
        *(s16x4*)&Zc[base] = pv;          // ekv at col
        *(s16x4*)&Zc[base + 1024] = pk;   // ek  at col+128
      }
    }
  }
}

// ---------------- fused attention + stats ----------------
// grid (32,32): 32 n-rows x 256 cols, K=1024 (chunked Zc), 4 waves, 4 blocks/CU
template<int USE16>
__global__ __launch_bounds__(256) void k_attn(
  const float* __restrict__ dist, const unsigned short* __restrict__ db16,
  const unsigned short* __restrict__ Zc, const unsigned short* __restrict__ sigq,
  float* __restrict__ x, float* __restrict__ partA,
  const float* __restrict__ log_scale, const float* __restrict__ alpha, int layer)
{
  union SM {
    struct { unsigned short A[2][4][32][8]; unsigned short B[2][4][256][8]; } st;
    float den[32][128];
  };
  __shared__ SM sm;
  int tid = threadIdx.x, wid = tid>>6, lane = tid&63;
  int l15 = lane&15, lg = lane>>4;
  int bb = blockIdx.y, t = blockIdx.x, n0 = t*32;
  float sc = log_scale[0]*alpha[layer];
  const unsigned short* Zb = Zc + ((size_t)bb << 18);
  int arow = (tid>>2)&31, ag = tid&3;
  int an = n0 + arow; if (an > 999) an = 999;
  const size_t drow = (size_t)(bb*1000 + an);

  f32x4 zf = {0.f,0.f,0.f,0.f};
  f32x4 acc[2][4];
#pragma unroll
  for (int i=0;i<2;i++)
#pragma unroll
    for (int j=0;j<4;j++) acc[i][j] = zf;

  auto issueB = [&](int kk, int buf){
#pragma unroll
    for (int t2=0;t2<4;++t2){
      int e = wid + t2*4, g2 = e&3, cb = e>>2;
      gl16(Zb + ((size_t)((kk*4 + g2)*256 + cb*64 + lane))*8, &sm.st.B[buf][g2][cb*64][0]);
    }
  };
  auto loadA = [&](int kk, float* v){
    int k0 = kk*32 + ag*8;
    if (USE16){
      bf16x8 r = *(const bf16x8*)(db16 + drow*1024 + k0);
#pragma unroll
      for (int e=0;e<8;e++) v[e] = b2f((unsigned short)r[e]);
    } else {
      const float* dp = dist + (size_t)drow*1000;
      if (k0 + 8 <= 1000){
        f32x4 a0 = *(const f32x4*)(dp + k0);
        f32x4 a1 = *(const f32x4*)(dp + k0 + 4);
#pragma unroll
        for (int e=0;e<4;e++){ v[e] = a0[e]; v[4+e] = a1[e]; }
      } else {
#pragma unroll
        for (int e=0;e<8;e++){
          int m = k0 + e; if (m > 999) m = 999;
          v[e] = dp[m];
        }
      }
    }
  };
  auto expwrite = [&](const float* v, int buf){
    bf16x8 w;
#pragma unroll
    for (int e=0;e<8;e++) w[e] = (short)f2b(__expf(sc*v[e]));
    *(bf16x8*)&sm.st.A[buf][ag][arow][0] = w;
  };
  auto compute = [&](int buf){
    bf16x8 af[2], bq[4];
#pragma unroll
    for (int i=0;i<2;i++) af[i] = *(const bf16x8*)&sm.st.A[buf][lg][i*16 + l15][0];
#pragma unroll
    for (int j=0;j<4;j++) bq[j] = *(const bf16x8*)&sm.st.B[buf][lg][wid*64 + j*16 + l15][0];
#pragma unroll
    for (int i=0;i<2;i++)
#pragma unroll
      for (int j=0;j<4;j++)
        acc[i][j] = mfma16(af[i], bq[j], acc[i][j]);
  };

  float av[8];
  issueB(0, 0);
  if (tid < 128) loadA(0, av);
  if (tid < 128) expwrite(av, 0);
  __syncthreads();
  for (int kk = 0; kk < 32; ++kk){
    int buf = kk & 1;
    float nv[8];
    if (kk < 31){
      issueB(kk+1, buf^1);
      if (tid < 128) loadA(kk+1, nv);
    }
    compute(buf);
    if (kk < 31 && tid < 128) expwrite(nv, buf^1);
    __syncthreads();
  }

  if (wid >= 2){
#pragma unroll
    for (int i=0;i<2;i++)
#pragma unroll
      for (int j=0;j<4;j++){
        int dcol = (wid-2)*64 + j*16 + l15;
#pragma unroll
        for (int r=0;r<4;r++)
          sm.den[i*16 + lg*4 + r][dcol] = acc[i][j][r];
      }
  }
  __syncthreads();
  if (wid < 2){
    float s1[4] = {0.f,0.f,0.f,0.f}, s2[4] = {0.f,0.f,0.f,0.f};
#pragma unroll
    for (int i=0;i<2;i++){
#pragma unroll
      for (int r=0;r<4;r++){
        int n = n0 + i*16 + lg*4 + r;
        if (n < 1000){
          size_t rowi = ((size_t)bb*1000 + n)*128;
#pragma unroll
          for (int j=0;j<4;j++){
            int d = wid*64 + j*16 + l15;
            float y = x[rowi + d] +
                      b2f(sigq[rowi + d]) * acc[i][j][r] / sm.den[i*16 + lg*4 + r][d];
            x[rowi + d] = y;
            s1[j] += y; s2[j] += y*y;
          }
        }
      }
    }
#pragma unroll
    for (int j=0;j<4;j++){
      s1[j] += __shfl_xor(s1[j], 16); s2[j] += __shfl_xor(s2[j], 16);
      s1[j] += __shfl_xor(s1[j], 32); s2[j] += __shfl_xor(s2[j], 32);
    }
    if (lg == 0){
#pragma unroll
      for (int j=0;j<4;j++){
        int d = wid*64 + j*16 + l15;
        size_t pi = (((size_t)bb*32 + t)*128 + d)*2;
        partA[pi] = s1[j]; partA[pi+1] = s2[j];
      }
    }
  }
}

// ---------------- FF1 + fused norm1: h1 = relu(inorm(x) @ W1^T + bw1) ----------------
// grid 512 (b*16 + 64-row tile), 512 thr (8 waves), BN=512, K=128
// side output: x1b = inorm(x) bf16 (residual for FF2)
__global__ __launch_bounds__(512) void k_ff1(
  const float* __restrict__ x, const float* __restrict__ partA,
  const float* __restrict__ g1, const float* __restrict__ b1,
  const unsigned short* __restrict__ W1b, const float* __restrict__ bw1,
  unsigned short* __restrict__ x1b, unsigned short* __restrict__ h1)
{
  __shared__ unsigned short LA[2][4][64][8];
  __shared__ unsigned short LB[2][4][512][8];
  __shared__ float sna[128], snc[128];
  int tid = threadIdx.x, wid = tid>>6, lane = tid&63;
  int l15 = lane&15, lg = lane>>4;
  int wm = wid>>2, wn = wid&3;
  int bt = blockIdx.x, b = bt>>4, t = bt&15;

  if (tid < 128){
    float s1 = 0.f, s2 = 0.f;
    for (int c = 0; c < 32; ++c){
      size_t pi = (((size_t)b*32 + c)*128 + tid)*2;
      s1 += partA[pi]; s2 += partA[pi+1];
    }
    float mean = s1 * 1e-3f;
    float var  = s2 * 1e-3f - mean*mean;
    float a = g1[tid] * rsqrtf(var + 1e-5f);
    sna[tid] = a; snc[tid] = b1[tid] - mean*a;
  }
  __syncthreads();

  f32x4 zf = {0.f,0.f,0.f,0.f};
  f32x4 acc[2][8];
#pragma unroll
  for (int i=0;i<2;i++)
#pragma unroll
    for (int j=0;j<8;j++) acc[i][j] = zf;

  auto stage = [&](int kk, int buf){
    int k0 = kk*32;
    if (tid < 256){
      int row = tid>>2, g2 = tid&3;
      int lr = t*64 + row;
      int rr = lr > 999 ? 999 : lr;
      const float* p = x + ((size_t)(b*1000 + rr))*128 + k0 + g2*8;
      f32x4 v0 = *(const f32x4*)p;
      f32x4 v1 = *(const f32x4*)(p + 4);
      bf16x8 w;
#pragma unroll
      for (int e=0;e<4;e++){
        int k = k0 + g2*8;
        w[e]   = (short)f2b(v0[e]*sna[k+e]   + snc[k+e]);
        w[4+e] = (short)f2b(v1[e]*sna[k+4+e] + snc[k+4+e]);
      }
      *(bf16x8*)&LA[buf][g2][row][0] = w;
      if (lr < 1000)
        *(bf16x8*)&x1b[((size_t)(b*1000 + lr))*128 + k0 + g2*8] = w;
    }
    // W1 staging: wave-uniform LDS dest (g2, nb uniform per wave), lane-contiguous dest
#pragma unroll
    for (int t2=0;t2<4;++t2){
      int e = wid*4 + t2;           // 0..31, uniform within wave
      int g2 = e & 3, nb = e >> 2;  // g2 0..3, nb 0..7
      gl16(W1b + (size_t)(nb*64 + lane)*128 + k0 + g2*8, &LB[buf][g2][nb*64][0]);
    }
  };
  auto compute = [&](int buf){
    bf16x8 af[2];
#pragma unroll
    for (int i=0;i<2;i++) af[i] = *(const bf16x8*)&LA[buf][lg][wm*32 + i*16 + l15][0];
#pragma unroll
    for (int j=0;j<8;j++){
      bf16x8 bq = *(const bf16x8*)&LB[buf][lg][wn*128 + j*16 + l15][0];
#pragma unroll
      for (int i=0;i<2;i++) acc[i][j] = mfma16(af[i], bq, acc[i][j]);
    }
  };

  stage(0, 0);
  __syncthreads();
  for (int kk = 0; kk < 4; ++kk){
    int buf = kk & 1;
    if (kk < 3) stage(kk+1, buf^1);
    compute(buf);
    __syncthreads();
  }

#pragma unroll
  for (int i=0;i<2;i++){
    int m4 = t*64 + wm*32 + i*16 + lg*4;
    if (m4 >= 1000) continue;
#pragma unroll
    for (int j=0;j<8;j++){
      int col = wn*128 + j*16 + l15;
      float bz = bw1[col];
#pragma unroll
      for (int r=0;r<4;r++){
        float v = acc[i][j][r] + bz;
        h1[(size_t)(b*1000 + m4 + r)*512 + col] = f2b(v > 0.f ? v : 0.f);
      }
    }
  }
}

// ---------------- FF2 + residual + stats: h1 @ W2^T + bw2 + x1b -> x, partF ----------------
// grid 512 (per-batch 64-row tiles), K=512
__global__ __launch_bounds__(256) void k_ff2(
  const unsigned short* __restrict__ h1, const unsigned short* __restrict__ W2b,
  const float* __restrict__ bw2, const unsigned short* __restrict__ x1b,
  float* __restrict__ x, float* __restrict__ partF)
{
  __shared__ unsigned short LA[2][4][64][8];
  __shared__ unsigned short LB[2][4][128][8];
  int tid = threadIdx.x, wid = tid>>6, lane = tid&63;
  int l15 = lane&15, lg = lane>>4;
  int wm = wid>>1, wn = wid&1;
  int bt = blockIdx.x, b = bt>>4, t = bt&15;
  int lrow = t*64 + lane; if (lrow > 999) lrow = 999;
  size_t arow = (size_t)(b*1000 + lrow);

  f32x4 zf = {0.f,0.f,0.f,0.f};
  f32x4 acc[2][4];
#pragma unroll
  for (int i=0;i<2;i++)
#pragma unroll
    for (int j=0;j<4;j++) acc[i][j] = zf;

  auto stage = [&](int kk, int buf){
    int k0 = kk*32;
    gl16(h1 + arow*512 + k0 + wid*8, &LA[buf][wid][0][0]);
#pragma unroll
    for (int t2=0;t2<2;++t2){
      int e = wid + t2*4, g2 = e>>1, nb = e&1;
      gl16(W2b + (size_t)(nb*64 + lane)*512 + k0 + g2*8, &LB[buf][g2][nb*64][0]);
    }
  };
  auto compute = [&](int buf){
    bf16x8 af[2];
#pragma unroll
    for (int i=0;i<2;i++) af[i] = *(const bf16x8*)&LA[buf][lg][wm*32 + i*16 + l15][0];
#pragma unroll
    for (int j=0;j<4;j++){
      bf16x8 bq = *(const bf16x8*)&LB[buf][lg][wn*64 + j*16 + l15][0];
#pragma unroll
      for (int i=0;i<2;i++) acc[i][j] = mfma16(af[i], bq, acc[i][j]);
    }
  };

  stage(0, 0);
  __syncthreads();
  for (int kk = 0; kk < 16; ++kk){
    int buf = kk & 1;
    if (kk < 15) stage(kk+1, buf^1);
    compute(buf);
    __syncthreads();
  }

  float s1[4] = {0.f,0.f,0.f,0.f}, s2[4] = {0.f,0.f,0.f,0.f};
#pragma unroll
  for (int i=0;i<2;i++){
    int m4 = t*64 + wm*32 + i*16 + lg*4;
    if (m4 >= 1000) continue;
#pragma unroll
    for (int j=0;j<4;j++){
      int col = wn*64 + j*16 + l15;
      float bz = bw2[col];
#pragma unroll
      for (int r=0;r<4;r++){
        size_t idx = (size_t)(b*1000 + m4 + r)*128 + col;
        float y = acc[i][j][r] + bz + b2f(x1b[idx]);
        x[idx] = y;
        s1[j] += y; s2[j] += y*y;
      }
    }
  }
#pragma unroll
  for (int j=0;j<4;j++){
    s1[j] += __shfl_xor(s1[j], 16); s2[j] += __shfl_xor(s2[j], 16);
    s1[j] += __shfl_xor(s1[j], 32); s2[j] += __shfl_xor(s2[j], 32);
  }
  if (lg == 0){
#pragma unroll
    for (int j=0;j<4;j++){
      int d = wn*64 + j*16 + l15;
      size_t pi = (((size_t)b*32 + t*2 + wm)*128 + d)*2;
      partF[pi] = s1[j]; partF[pi+1] = s2[j];
    }
  }
}

extern "C" void kernel_launch(void* const* d_in, const int* in_sizes, int n_in,
                              void* d_out, int out_size, void* d_ws, size_t ws_size,
                              hipStream_t stream) {
  const float* data = (const float*)d_in[0];
  const float* dist = (const float*)d_in[1];
  const float* log_scale = (const float*)d_in[2];
  const float* We = (const float*)d_in[3];
  const float* be = (const float*)d_in[4];
  const float* Wq = (const float*)d_in[5];
  const float* Wk = (const float*)d_in[6];
  const float* Wv = (const float*)d_in[7];
  const float* g1 = (const float*)d_in[8];
  const float* b1 = (const float*)d_in[9];
  const float* W1 = (const float*)d_in[10];
  const float* bw1 = (const float*)d_in[11];
  const float* W2 = (const float*)d_in[12];
  const float* bw2 = (const float*)d_in[13];
  const float* g2 = (const float*)d_in[14];
  const float* b2 = (const float*)d_in[15];
  const float* alpha = (const float*)d_in[16];
  float* dout = (float*)d_out;

  char* ws = (char*)d_ws;
  size_t off = 0;
  auto alloc = [&](size_t bytes) -> void* {
    void* p = ws + off; off += (bytes + 255) & ~(size_t)255; return p;
  };
  unsigned short* xb  = (unsigned short*)alloc(8192000);    // [32000][128] bf16
  float* x            = (float*)alloc(16384000);            // [32000][128] f32
  unsigned short* sigq= (unsigned short*)alloc(8192000);    // [32000][128] bf16
  unsigned short* Zc  = (unsigned short*)alloc(16777216);   // [32][128][256][8] bf16
  unsigned short* h1  = (unsigned short*)alloc(32768000);   // [32000][512] bf16
  unsigned short* x1b = (unsigned short*)alloc(8192000);    // [32000][128] bf16
  float* partA        = (float*)alloc(1048576);             // [32][32][128][2]
  float* partF        = (float*)alloc(1048576);             // [32][32][128][2]
  unsigned short* wqb = (unsigned short*)alloc(196608);
  unsigned short* wkb = (unsigned short*)alloc(196608);
  unsigned short* wvb = (unsigned short*)alloc(196608);
  unsigned short* w1b = (unsigned short*)alloc(786432);
  unsigned short* w2b = (unsigned short*)alloc(786432);
  if (off > ws_size) return;
  unsigned short* db16p = nullptr;
  if (ws_size >= off + 131072256) db16p = (unsigned short*)alloc(131072000); // [32000][1024] bf16

  hipMemsetAsync(Zc, 0, 16777216, stream);   // m-pad chunks stay zero
  k_cvt5<<<4224, 256, 0, stream>>>(Wq, Wk, Wv, W1, W2, wqb, wkb, wvb, w1b, w2b);
  if (db16p) k_cvtdist<<<16000, 256, 0, stream>>>(dist, db16p);
  k_embed<<<16000, 256, 0, stream>>>(data, We, be, x, xb);

  for (int i = 0; i < LCOUNT; ++i){
    k_qkv<<<dim3(512,2), 256, 0, stream>>>(xb, wqb + i*16384, wkb + i*16384,
                                           wvb + i*16384, sigq, Zc);
    if (db16p)
      k_attn<1><<<dim3(32,32), 256, 0, stream>>>(dist, db16p, Zc, sigq, x, partA,
                                                 log_scale, alpha, i);
    else
      k_attn<0><<<dim3(32,32), 256, 0, stream>>>(dist, nullptr, Zc, sigq, x, partA,
                                                 log_scale, alpha, i);
    k_ff1<<<512, 512, 0, stream>>>(x, partA, g1 + i*128, b1 + i*128,
                                   w1b + i*65536, bw1 + i*512, x1b, h1);
    k_ff2<<<512, 256, 0, stream>>>(h1, w2b + i*65536, bw2 + i*128, x1b, x, partF);
    k_napply<<<4000, 256, 0, stream>>>(x, partF, 32, g2 + i*128, b2 + i*128,
                                       x, xb, (i == LCOUNT-1) ? dout : nullptr);
  }
}

// Round 6
// 858.101 us; speedup vs baseline: 1.3007x; 1.0811x over previous
//
#include <hip/hip_runtime.h>
#include <hip/hip_bf16.h>

typedef __attribute__((ext_vector_type(4))) float f32x4;
typedef __attribute__((ext_vector_type(8))) short bf16x8;
typedef __attribute__((ext_vector_type(4))) short s16x4;

#define LCOUNT 6

static __device__ __forceinline__ unsigned short f2b(float f){
  __hip_bfloat16 h = __float2bfloat16(f);
  return __builtin_bit_cast(unsigned short, h);
}
static __device__ __forceinline__ float b2f(unsigned short u){
  unsigned int x = ((unsigned int)u) << 16;
  return __builtin_bit_cast(float, x);
}
static __device__ __forceinline__ void gl16(const void* g, void* l){
  __builtin_amdgcn_global_load_lds(
      (const __attribute__((address_space(1))) void*)g,
      (__attribute__((address_space(3))) void*)l, 16, 0, 0);
}
static __device__ __forceinline__ f32x4 mfma16(bf16x8 a, bf16x8 b, f32x4 c){
  return __builtin_amdgcn_mfma_f32_16x16x32_bf16(a, b, c, 0, 0, 0);
}

// ---------------- setup kernels ----------------
__global__ void k_cvt5(const float* __restrict__ Wq, const float* __restrict__ Wk,
                       const float* __restrict__ Wv, const float* __restrict__ W1,
                       const float* __restrict__ W2,
                       unsigned short* __restrict__ wqb, unsigned short* __restrict__ wkb,
                       unsigned short* __restrict__ wvb, unsigned short* __restrict__ w1b,
                       unsigned short* __restrict__ w2b){
  int i = blockIdx.x*256 + threadIdx.x;
  if (i < 98304) wqb[i] = f2b(Wq[i]);
  else if (i < 196608) wkb[i-98304] = f2b(Wk[i-98304]);
  else if (i < 294912) wvb[i-196608] = f2b(Wv[i-196608]);
  else if (i < 688128) w1b[i-294912] = f2b(W1[i-294912]);
  else w2b[i-688128] = f2b(W2[i-688128]);
}

__global__ void k_cvtdist(const float* __restrict__ dist, unsigned short* __restrict__ db){
  int t = blockIdx.x*256 + threadIdx.x;
  int row = t >> 7, ch = t & 127;
  bf16x8 w;
  if (ch >= 125){
#pragma unroll
    for (int e=0;e<8;e++) w[e] = 0;
  } else {
    const float* p = dist + (size_t)row*1000 + ch*8;
    f32x4 a = *(const f32x4*)p;
    f32x4 b = *(const f32x4*)(p + 4);
#pragma unroll
    for (int e=0;e<4;e++){ w[e] = (short)f2b(a[e]); w[4+e] = (short)f2b(b[e]); }
  }
  *(bf16x8*)&db[(size_t)row*1024 + ch*8] = w;
}

__global__ void k_embed(const float* __restrict__ data, const float* __restrict__ We,
                        const float* __restrict__ be, float* __restrict__ x,
                        unsigned short* __restrict__ xb){
  int idx = blockIdx.x*256 + threadIdx.x;
  int d = idx & 127, bn = idx >> 7;
  float v = data[bn*2]*We[d*2] + data[bn*2+1]*We[d*2+1] + be[d];
  x[idx] = v; xb[idx] = f2b(v);
}

// ---------------- norm-scale reduce: part -> na,nc [32][128] ----------------
__global__ void k_scale(const float* __restrict__ part, int cnt,
                        const float* __restrict__ g, const float* __restrict__ beta,
                        float* __restrict__ na, float* __restrict__ nc){
  int b = blockIdx.x, d = threadIdx.x;   // 32 x 128
  float s1 = 0.f, s2 = 0.f;
  for (int c = 0; c < cnt; ++c){
    size_t pi = (((size_t)b*cnt + c)*128 + d)*2;
    s1 += part[pi]; s2 += part[pi+1];
  }
  float mean = s1 * 1e-3f;
  float var  = s2 * 1e-3f - mean*mean;
  float a = g[d] * rsqrtf(var + 1e-5f);
  na[b*128 + d] = a; nc[b*128 + d] = beta[d] - mean*a;
}

// ---------------- final apply: dout = x*na+nc ----------------
__global__ __launch_bounds__(256) void k_fapply(
  const float* __restrict__ x, const float* __restrict__ na,
  const float* __restrict__ nc, float* __restrict__ dout){
  int blk = blockIdx.x, tid = threadIdx.x;
  int b = blk / 125;
  size_t base = (size_t)blk*1024 + tid*4;
  int d0 = (tid*4) & 127;
  f32x4 v = *(const f32x4*)&x[base];
  f32x4 o;
#pragma unroll
  for (int e=0;e<4;e++) o[e] = v[e]*na[b*128 + d0 + e] + nc[b*128 + d0 + e];
  *(f32x4*)&dout[base] = o;
}

// ---------------- fused QKV GEMM (+inline norm2 of prev layer) ----------------
// grid (512, 2): x = b*16 + t(64 rows), y: 0=Q->sigq, 1=KV->Zc
template<int NORM>
__global__ __launch_bounds__(256) void k_qkv(
  const unsigned short* __restrict__ xb, const float* __restrict__ x,
  const float* __restrict__ na2, const float* __restrict__ nc2,
  const unsigned short* __restrict__ Wqb, const unsigned short* __restrict__ Wkb,
  const unsigned short* __restrict__ Wvb,
  unsigned short* __restrict__ sigq, unsigned short* __restrict__ Zc)
{
  __shared__ unsigned short LA[2*2048];          // 2 layouts via constexpr index
  __shared__ unsigned short LB[2][4][256][8];
  __shared__ float sna[128], snc[128];
  int tid = threadIdx.x, wid = tid>>6, lane = tid&63;
  int l15 = lane&15, lg = lane>>4;
  int wm = wid>>1, wn = wid&1;
  int bt = blockIdx.x, b = bt>>4, t = bt&15;
  int kv = blockIdx.y;
  int lrow = t*64 + lane; if (lrow > 999) lrow = 999;
  size_t arow = (size_t)(b*1000 + lrow);

  if (NORM){
    if (tid < 128){ sna[tid] = na2[b*128 + tid]; snc[tid] = nc2[b*128 + tid]; }
    __syncthreads();
  }

  f32x4 zf = {0.f,0.f,0.f,0.f};
  f32x4 acc[2][4], acc2[2][4];
#pragma unroll
  for (int i=0;i<2;i++)
#pragma unroll
    for (int j=0;j<4;j++){ acc[i][j] = zf; acc2[i][j] = zf; }

  auto stage = [&](int kk, int buf){
    int k0 = kk*32;
    if (NORM){
      int row = tid>>2, g2 = tid&3;
      int lr = t*64 + row; int rr = lr > 999 ? 999 : lr;
      const float* p = x + ((size_t)(b*1000 + rr))*128 + k0 + g2*8;
      f32x4 v0 = *(const f32x4*)p;
      f32x4 v1 = *(const f32x4*)(p + 4);
      bf16x8 w;
#pragma unroll
      for (int e=0;e<4;e++){
        int k = k0 + g2*8;
        w[e]   = (short)f2b(v0[e]*sna[k+e]   + snc[k+e]);
        w[4+e] = (short)f2b(v1[e]*sna[k+4+e] + snc[k+4+e]);
      }
      *(bf16x8*)&LA[buf*2048 + row*32 + g2*8] = w;   // row-major [64][4][8]
    } else {
      gl16(xb + arow*128 + k0 + wid*8, &LA[buf*2048 + wid*512]);  // [4][64][8]
    }
    if (kv == 0){
#pragma unroll
      for (int t2=0;t2<2;++t2){
        int e = wid + t2*4, g2 = e>>1, nb = e&1;
        gl16(Wqb + (size_t)(nb*64+lane)*128 + k0 + g2*8, &LB[buf][g2][nb*64][0]);
      }
    } else {
#pragma unroll
      for (int t2=0;t2<4;++t2){
        int e = wid + t2*4, g2 = e&3, nb = e>>2;
        const unsigned short* src = (nb < 2)
          ? Wkb + (size_t)(nb*64+lane)*128 + k0 + g2*8
          : Wvb + (size_t)((nb-2)*64+lane)*128 + k0 + g2*8;
        gl16(src, &LB[buf][g2][nb*64][0]);
      }
    }
  };
  auto compute = [&](int buf){
    bf16x8 af[2];
#pragma unroll
    for (int i=0;i<2;i++){
      int row = wm*32 + i*16 + l15;
      af[i] = NORM ? *(const bf16x8*)&LA[buf*2048 + row*32 + lg*8]
                   : *(const bf16x8*)&LA[buf*2048 + lg*512 + row*8];
    }
#pragma unroll
    for (int j=0;j<4;j++){
      bf16x8 bq = *(const bf16x8*)&LB[buf][lg][wn*64 + j*16 + l15][0];
#pragma unroll
      for (int i=0;i<2;i++) acc[i][j] = mfma16(af[i], bq, acc[i][j]);
      if (kv){
        bf16x8 bv = *(const bf16x8*)&LB[buf][lg][128 + wn*64 + j*16 + l15][0];
#pragma unroll
        for (int i=0;i<2;i++) acc2[i][j] = mfma16(af[i], bv, acc2[i][j]);
      }
    }
  };

  stage(0, 0);
  __syncthreads();
  for (int kk = 0; kk < 4; ++kk){
    int buf = kk & 1;
    if (kk < 3) stage(kk+1, buf^1);
    compute(buf);
    __syncthreads();
  }

#pragma unroll
  for (int i=0;i<2;i++){
    int m4 = t*64 + wm*32 + i*16 + lg*4;
    if (m4 >= 1000) continue;
#pragma unroll
    for (int j=0;j<4;j++){
      int col = wn*64 + j*16 + l15;
      if (kv == 0){
#pragma unroll
        for (int r=0;r<4;r++)
          sigq[(size_t)(b*1000 + m4 + r)*128 + col] = f2b(1.f/(1.f + __expf(-acc[i][j][r])));
      } else {
        s16x4 pv, pk;
#pragma unroll
        for (int r=0;r<4;r++){
          float ek = __expf(acc[i][j][r]);
          pk[r] = (short)f2b(ek);
          pv[r] = (short)f2b(ek * acc2[i][j][r]);
        }
        size_t base = ((size_t)(b*128 + (m4>>3))*256 + col)*8 + ((m4>>2)&1)*4;
        *(s16x4*)&Zc[base] = pv;
        *(s16x4*)&Zc[base + 1024] = pk;
      }
    }
  }
}

// ---------------- fused attention (+inline norm2) + stats ----------------
// grid (16,32): 64 n-rows x 256 cols, K=1024, 4 waves, 40KB LDS -> 4 blocks/CU
template<int NORM, int USE16>
__global__ __launch_bounds__(256) void k_attn(
  const float* __restrict__ dist, const unsigned short* __restrict__ db16,
  const unsigned short* __restrict__ Zc, const unsigned short* __restrict__ sigq,
  float* __restrict__ x, float* __restrict__ partA,
  const float* __restrict__ na2, const float* __restrict__ nc2,
  const float* __restrict__ log_scale, const float* __restrict__ alpha, int layer)
{
  union SM {
    struct { unsigned short A[2][64][4][8]; unsigned short B[2][4][256][8]; } st;
    float den[64][128];
  };
  __shared__ SM sm;
  int tid = threadIdx.x, wid = tid>>6, lane = tid&63;
  int l15 = lane&15, lg = lane>>4;
  int bb = blockIdx.y, t = blockIdx.x, n0 = t*64;
  float sc = log_scale[0]*alpha[layer];
  const unsigned short* Zb = Zc + ((size_t)bb << 18);
  int arow = tid>>2, ag = tid&3;
  int an = n0 + arow; if (an > 999) an = 999;
  const size_t drow = (size_t)(bb*1000 + an);

  f32x4 zf = {0.f,0.f,0.f,0.f};
  f32x4 acc[4][4];
#pragma unroll
  for (int i=0;i<4;i++)
#pragma unroll
    for (int j=0;j<4;j++) acc[i][j] = zf;

  auto issueB = [&](int kk, int buf){
#pragma unroll
    for (int t2=0;t2<4;++t2){
      int e = wid + t2*4, g2 = e&3, cb = e>>2;
      gl16(Zb + ((size_t)((kk*4 + g2)*256 + cb*64 + lane))*8, &sm.st.B[buf][g2][cb*64][0]);
    }
  };
  auto loadA = [&](int kk, float* v){
    int k0 = kk*32 + ag*8;
    if (USE16){
      bf16x8 r = *(const bf16x8*)(db16 + drow*1024 + k0);
#pragma unroll
      for (int e=0;e<8;e++) v[e] = b2f((unsigned short)r[e]);
    } else {
      const float* dp = dist + drow*1000;
      if (k0 + 8 <= 1000){
        f32x4 a0 = *(const f32x4*)(dp + k0);
        f32x4 a1 = *(const f32x4*)(dp + k0 + 4);
#pragma unroll
        for (int e=0;e<4;e++){ v[e] = a0[e]; v[4+e] = a1[e]; }
      } else {
#pragma unroll
        for (int e=0;e<8;e++){
          int m = k0 + e; if (m > 999) m = 999;
          v[e] = dp[m];
        }
      }
    }
  };
  auto expwrite = [&](const float* v, int buf){
    bf16x8 w;
#pragma unroll
    for (int e=0;e<8;e++) w[e] = (short)f2b(__expf(sc*v[e]));
    *(bf16x8*)&sm.st.A[buf][arow][ag][0] = w;   // row-major: conflict-free write
  };
  auto compute = [&](int buf){
    bf16x8 af[4], bq[4];
#pragma unroll
    for (int i=0;i<4;i++) af[i] = *(const bf16x8*)&sm.st.A[buf][i*16 + l15][lg][0];
#pragma unroll
    for (int j=0;j<4;j++) bq[j] = *(const bf16x8*)&sm.st.B[buf][lg][wid*64 + j*16 + l15][0];
#pragma unroll
    for (int i=0;i<4;i++)
#pragma unroll
      for (int j=0;j<4;j++)
        acc[i][j] = mfma16(af[i], bq[j], acc[i][j]);
  };

  float av[8];
  issueB(0, 0);
  loadA(0, av);
  expwrite(av, 0);
  __syncthreads();
  for (int kk = 0; kk < 32; ++kk){
    int buf = kk & 1;
    float nv[8];
    if (kk < 31){ issueB(kk+1, buf^1); loadA(kk+1, nv); }
    compute(buf);
    if (kk < 31) expwrite(nv, buf^1);
    __syncthreads();
  }

  if (wid >= 2){
#pragma unroll
    for (int i=0;i<4;i++)
#pragma unroll
      for (int j=0;j<4;j++){
        int dcol = (wid-2)*64 + j*16 + l15;
#pragma unroll
        for (int r=0;r<4;r++)
          sm.den[i*16 + lg*4 + r][dcol] = acc[i][j][r];
      }
  }
  __syncthreads();
  if (wid < 2){
    float nav[4], ncv[4];
    if (NORM){
#pragma unroll
      for (int j=0;j<4;j++){
        int d = wid*64 + j*16 + l15;
        nav[j] = na2[bb*128 + d]; ncv[j] = nc2[bb*128 + d];
      }
    }
    float s1[4] = {0.f,0.f,0.f,0.f}, s2[4] = {0.f,0.f,0.f,0.f};
#pragma unroll
    for (int i=0;i<4;i++){
#pragma unroll
      for (int r=0;r<4;r++){
        int n = n0 + i*16 + lg*4 + r;
        if (n < 1000){
          size_t rowi = ((size_t)bb*1000 + n)*128;
#pragma unroll
          for (int j=0;j<4;j++){
            int d = wid*64 + j*16 + l15;
            float xv = x[rowi + d];
            if (NORM) xv = xv*nav[j] + ncv[j];
            float y = xv + b2f(sigq[rowi + d]) * acc[i][j][r] / sm.den[i*16 + lg*4 + r][d];
            x[rowi + d] = y;
            s1[j] += y; s2[j] += y*y;
          }
        }
      }
    }
#pragma unroll
    for (int j=0;j<4;j++){
      s1[j] += __shfl_xor(s1[j], 16); s2[j] += __shfl_xor(s2[j], 16);
      s1[j] += __shfl_xor(s1[j], 32); s2[j] += __shfl_xor(s2[j], 32);
    }
    if (lg == 0){
#pragma unroll
      for (int j=0;j<4;j++){
        int d = wid*64 + j*16 + l15;
        size_t pi = (((size_t)bb*16 + t)*128 + d)*2;
        partA[pi] = s1[j]; partA[pi+1] = s2[j];
      }
    }
  }
}

// ---------------- FF1 + fused norm1 ----------------
// grid 512 (b*16 + t), 512 thr, BN=512, K=128; side out: x1 = inorm1(x) f32
__global__ __launch_bounds__(512) void k_ff1(
  const float* __restrict__ x, const float* __restrict__ partA,
  const float* __restrict__ g1, const float* __restrict__ b1,
  const unsigned short* __restrict__ W1b, const float* __restrict__ bw1,
  float* __restrict__ x1, unsigned short* __restrict__ h1)
{
  __shared__ unsigned short LA[2][64][4][8];    // row-major
  __shared__ unsigned short LB[2][4][512][8];
  __shared__ float sna[128], snc[128];
  int tid = threadIdx.x, wid = tid>>6, lane = tid&63;
  int l15 = lane&15, lg = lane>>4;
  int wm = wid>>2, wn = wid&3;
  int bt = blockIdx.x, b = bt>>4, t = bt&15;

  if (tid < 128){
    float s1 = 0.f, s2 = 0.f;
    for (int c = 0; c < 16; ++c){
      size_t pi = (((size_t)b*16 + c)*128 + tid)*2;
      s1 += partA[pi]; s2 += partA[pi+1];
    }
    float mean = s1 * 1e-3f;
    float var  = s2 * 1e-3f - mean*mean;
    float a = g1[tid] * rsqrtf(var + 1e-5f);
    sna[tid] = a; snc[tid] = b1[tid] - mean*a;
  }
  __syncthreads();

  f32x4 zf = {0.f,0.f,0.f,0.f};
  f32x4 acc[2][8];
#pragma unroll
  for (int i=0;i<2;i++)
#pragma unroll
    for (int j=0;j<8;j++) acc[i][j] = zf;

  auto stage = [&](int kk, int buf){
    int k0 = kk*32;
    if (tid < 256){
      int row = tid>>2, g2 = tid&3;
      int lr = t*64 + row;
      int rr = lr > 999 ? 999 : lr;
      const float* p = x + ((size_t)(b*1000 + rr))*128 + k0 + g2*8;
      f32x4 v0 = *(const f32x4*)p;
      f32x4 v1 = *(const f32x4*)(p + 4);
      f32x4 o0, o1;
      bf16x8 w;
#pragma unroll
      for (int e=0;e<4;e++){
        int k = k0 + g2*8;
        o0[e] = v0[e]*sna[k+e]   + snc[k+e];
        o1[e] = v1[e]*sna[k+4+e] + snc[k+4+e];
        w[e]   = (short)f2b(o0[e]);
        w[4+e] = (short)f2b(o1[e]);
      }
      *(bf16x8*)&LA[buf][row][g2][0] = w;
      if (lr < 1000){
        float* q = x1 + ((size_t)(b*1000 + lr))*128 + k0 + g2*8;
        *(f32x4*)q = o0; *(f32x4*)(q+4) = o1;
      }
    }
#pragma unroll
    for (int t2=0;t2<4;++t2){
      int e = wid*4 + t2;           // wave-uniform
      int g2 = e & 3, nb = e >> 2;
      gl16(W1b + (size_t)(nb*64 + lane)*128 + k0 + g2*8, &LB[buf][g2][nb*64][0]);
    }
  };
  auto compute = [&](int buf){
    bf16x8 af[2];
#pragma unroll
    for (int i=0;i<2;i++) af[i] = *(const bf16x8*)&LA[buf][wm*32 + i*16 + l15][lg][0];
#pragma unroll
    for (int j=0;j<8;j++){
      bf16x8 bq = *(const bf16x8*)&LB[buf][lg][wn*128 + j*16 + l15][0];
#pragma unroll
      for (int i=0;i<2;i++) acc[i][j] = mfma16(af[i], bq, acc[i][j]);
    }
  };

  stage(0, 0);
  __syncthreads();
  for (int kk = 0; kk < 4; ++kk){
    int buf = kk & 1;
    if (kk < 3) stage(kk+1, buf^1);
    compute(buf);
    __syncthreads();
  }

#pragma unroll
  for (int i=0;i<2;i++){
    int m4 = t*64 + wm*32 + i*16 + lg*4;
    if (m4 >= 1000) continue;
#pragma unroll
    for (int j=0;j<8;j++){
      int col = wn*128 + j*16 + l15;
      float bz = bw1[col];
#pragma unroll
      for (int r=0;r<4;r++){
        float v = acc[i][j][r] + bz;
        h1[(size_t)(b*1000 + m4 + r)*512 + col] = f2b(v > 0.f ? v : 0.f);
      }
    }
  }
}

// ---------------- FF2 + residual(f32) + stats ----------------
// grid 512, K=512
__global__ __launch_bounds__(256) void k_ff2(
  const unsigned short* __restrict__ h1, const unsigned short* __restrict__ W2b,
  const float* __restrict__ bw2, const float* __restrict__ x1,
  float* __restrict__ x, float* __restrict__ partF)
{
  __shared__ unsigned short LA[2][4][64][8];
  __shared__ unsigned short LB[2][4][128][8];
  int tid = threadIdx.x, wid = tid>>6, lane = tid&63;
  int l15 = lane&15, lg = lane>>4;
  int wm = wid>>1, wn = wid&1;
  int bt = blockIdx.x, b = bt>>4, t = bt&15;
  int lrow = t*64 + lane; if (lrow > 999) lrow = 999;
  size_t arow = (size_t)(b*1000 + lrow);

  f32x4 zf = {0.f,0.f,0.f,0.f};
  f32x4 acc[2][4];
#pragma unroll
  for (int i=0;i<2;i++)
#pragma unroll
    for (int j=0;j<4;j++) acc[i][j] = zf;

  auto stage = [&](int kk, int buf){
    int k0 = kk*32;
    gl16(h1 + arow*512 + k0 + wid*8, &LA[buf][wid][0][0]);
#pragma unroll
    for (int t2=0;t2<2;++t2){
      int e = wid + t2*4, g2 = e>>1, nb = e&1;
      gl16(W2b + (size_t)(nb*64 + lane)*512 + k0 + g2*8, &LB[buf][g2][nb*64][0]);
    }
  };
  auto compute = [&](int buf){
    bf16x8 af[2];
#pragma unroll
    for (int i=0;i<2;i++) af[i] = *(const bf16x8*)&LA[buf][lg][wm*32 + i*16 + l15][0];
#pragma unroll
    for (int j=0;j<4;j++){
      bf16x8 bq = *(const bf16x8*)&LB[buf][lg][wn*64 + j*16 + l15][0];
#pragma unroll
      for (int i=0;i<2;i++) acc[i][j] = mfma16(af[i], bq, acc[i][j]);
    }
  };

  stage(0, 0);
  __syncthreads();
  for (int kk = 0; kk < 16; ++kk){
    int buf = kk & 1;
    if (kk < 15) stage(kk+1, buf^1);
    compute(buf);
    __syncthreads();
  }

  float s1[4] = {0.f,0.f,0.f,0.f}, s2[4] = {0.f,0.f,0.f,0.f};
#pragma unroll
  for (int i=0;i<2;i++){
    int m4 = t*64 + wm*32 + i*16 + lg*4;
    if (m4 >= 1000) continue;
#pragma unroll
    for (int j=0;j<4;j++){
      int col = wn*64 + j*16 + l15;
      float bz = bw2[col];
#pragma unroll
      for (int r=0;r<4;r++){
        size_t idx = (size_t)(b*1000 + m4 + r)*128 + col;
        float y = acc[i][j][r] + bz + x1[idx];
        x[idx] = y;
        s1[j] += y; s2[j] += y*y;
      }
    }
  }
#pragma unroll
  for (int j=0;j<4;j++){
    s1[j] += __shfl_xor(s1[j], 16); s2[j] += __shfl_xor(s2[j], 16);
    s1[j] += __shfl_xor(s1[j], 32); s2[j] += __shfl_xor(s2[j], 32);
  }
  if (lg == 0){
#pragma unroll
    for (int j=0;j<4;j++){
      int d = wn*64 + j*16 + l15;
      size_t pi = (((size_t)b*32 + t*2 + wm)*128 + d)*2;
      partF[pi] = s1[j]; partF[pi+1] = s2[j];
    }
  }
}

extern "C" void kernel_launch(void* const* d_in, const int* in_sizes, int n_in,
                              void* d_out, int out_size, void* d_ws, size_t ws_size,
                              hipStream_t stream) {
  const float* data = (const float*)d_in[0];
  const float* dist = (const float*)d_in[1];
  const float* log_scale = (const float*)d_in[2];
  const float* We = (const float*)d_in[3];
  const float* be = (const float*)d_in[4];
  const float* Wq = (const float*)d_in[5];
  const float* Wk = (const float*)d_in[6];
  const float* Wv = (const float*)d_in[7];
  const float* g1 = (const float*)d_in[8];
  const float* b1 = (const float*)d_in[9];
  const float* W1 = (const float*)d_in[10];
  const float* bw1 = (const float*)d_in[11];
  const float* W2 = (const float*)d_in[12];
  const float* bw2 = (const float*)d_in[13];
  const float* g2 = (const float*)d_in[14];
  const float* b2 = (const float*)d_in[15];
  const float* alpha = (const float*)d_in[16];
  float* dout = (float*)d_out;

  char* ws = (char*)d_ws;
  size_t off = 0;
  auto alloc = [&](size_t bytes) -> void* {
    void* p = ws + off; off += (bytes + 255) & ~(size_t)255; return p;
  };
  unsigned short* xb  = (unsigned short*)alloc(8192000);    // [32000][128] bf16
  float* x            = (float*)alloc(16384000);            // [32000][128] f32
  unsigned short* sigq= (unsigned short*)alloc(8192000);    // [32000][128] bf16
  unsigned short* Zc  = (unsigned short*)alloc(16777216);   // [32][128][256][8] bf16
  unsigned short* h1  = (unsigned short*)alloc(32768000);   // [32000][512] bf16
  float* x1           = (float*)alloc(16384000);            // [32000][128] f32
  float* partA        = (float*)alloc(524288);              // [32][16][128][2]
  float* partF        = (float*)alloc(1048576);             // [32][32][128][2]
  float* na2          = (float*)alloc(16384);
  float* nc2          = (float*)alloc(16384);
  unsigned short* wqb = (unsigned short*)alloc(196608);
  unsigned short* wkb = (unsigned short*)alloc(196608);
  unsigned short* wvb = (unsigned short*)alloc(196608);
  unsigned short* w1b = (unsigned short*)alloc(786432);
  unsigned short* w2b = (unsigned short*)alloc(786432);
  if (off > ws_size) return;
  unsigned short* db16p = nullptr;
  if (ws_size >= off + 131072256) db16p = (unsigned short*)alloc(131072000); // [32000][1024] bf16

  hipMemsetAsync(Zc, 0, 16777216, stream);
  k_cvt5<<<4224, 256, 0, stream>>>(Wq, Wk, Wv, W1, W2, wqb, wkb, wvb, w1b, w2b);
  if (db16p) k_cvtdist<<<16000, 256, 0, stream>>>(dist, db16p);
  k_embed<<<16000, 256, 0, stream>>>(data, We, be, x, xb);

  for (int i = 0; i < LCOUNT; ++i){
    if (i > 0)
      k_scale<<<32, 128, 0, stream>>>(partF, 32, g2 + (i-1)*128, b2 + (i-1)*128, na2, nc2);
    if (i == 0)
      k_qkv<0><<<dim3(512,2), 256, 0, stream>>>(xb, x, nullptr, nullptr,
                                                wqb + i*16384, wkb + i*16384, wvb + i*16384,
                                                sigq, Zc);
    else
      k_qkv<1><<<dim3(512,2), 256, 0, stream>>>(nullptr, x, na2, nc2,
                                                wqb + i*16384, wkb + i*16384, wvb + i*16384,
                                                sigq, Zc);
    if (i == 0){
      if (db16p) k_attn<0,1><<<dim3(16,32), 256, 0, stream>>>(dist, db16p, Zc, sigq, x, partA,
                                                              nullptr, nullptr, log_scale, alpha, i);
      else       k_attn<0,0><<<dim3(16,32), 256, 0, stream>>>(dist, nullptr, Zc, sigq, x, partA,
                                                              nullptr, nullptr, log_scale, alpha, i);
    } else {
      if (db16p) k_attn<1,1><<<dim3(16,32), 256, 0, stream>>>(dist, db16p, Zc, sigq, x, partA,
                                                              na2, nc2, log_scale, alpha, i);
      else       k_attn<1,0><<<dim3(16,32), 256, 0, stream>>>(dist, nullptr, Zc, sigq, x, partA,
                                                              na2, nc2, log_scale, alpha, i);
    }
    k_ff1<<<512, 512, 0, stream>>>(x, partA, g1 + i*128, b1 + i*128,
                                   w1b + i*65536, bw1 + i*512, x1, h1);
    k_ff2<<<512, 256, 0, stream>>>(h1, w2b + i*65536, bw2 + i*128, x1, x, partF);
  }
  k_scale<<<32, 128, 0, stream>>>(partF, 32, g2 + 5*128, b2 + 5*128, na2, nc2);
  k_fapply<<<4000, 256, 0, stream>>>(x, na2, nc2, dout);
}

// Round 7
// 845.236 us; speedup vs baseline: 1.3205x; 1.0152x over previous
//
#include <hip/hip_runtime.h>
#include <hip/hip_bf16.h>

typedef __attribute__((ext_vector_type(4))) float f32x4;
typedef __attribute__((ext_vector_type(8))) short bf16x8;
typedef __attribute__((ext_vector_type(4))) short s16x4;

#define LCOUNT 6

static __device__ __forceinline__ unsigned short f2b(float f){
  __hip_bfloat16 h = __float2bfloat16(f);
  return __builtin_bit_cast(unsigned short, h);
}
static __device__ __forceinline__ float b2f(unsigned short u){
  unsigned int x = ((unsigned int)u) << 16;
  return __builtin_bit_cast(float, x);
}
static __device__ __forceinline__ void gl16(const void* g, void* l){
  __builtin_amdgcn_global_load_lds(
      (const __attribute__((address_space(1))) void*)g,
      (__attribute__((address_space(3))) void*)l, 16, 0, 0);
}
static __device__ __forceinline__ f32x4 mfma16(bf16x8 a, bf16x8 b, f32x4 c){
  return __builtin_amdgcn_mfma_f32_16x16x32_bf16(a, b, c, 0, 0, 0);
}

// ---------------- setup kernels ----------------
__global__ void k_cvt5(const float* __restrict__ Wq, const float* __restrict__ Wk,
                       const float* __restrict__ Wv, const float* __restrict__ W1,
                       const float* __restrict__ W2,
                       unsigned short* __restrict__ wqb, unsigned short* __restrict__ wkb,
                       unsigned short* __restrict__ wvb, unsigned short* __restrict__ w1b,
                       unsigned short* __restrict__ w2b){
  int i = blockIdx.x*256 + threadIdx.x;
  if (i < 98304) wqb[i] = f2b(Wq[i]);
  else if (i < 196608) wkb[i-98304] = f2b(Wk[i-98304]);
  else if (i < 294912) wvb[i-196608] = f2b(Wv[i-196608]);
  else if (i < 688128) w1b[i-294912] = f2b(W1[i-294912]);
  else w2b[i-688128] = f2b(W2[i-688128]);
}

__global__ void k_cvtdist(const float* __restrict__ dist, unsigned short* __restrict__ db){
  int t = blockIdx.x*256 + threadIdx.x;
  int row = t >> 7, ch = t & 127;
  bf16x8 w;
  if (ch >= 125){
#pragma unroll
    for (int e=0;e<8;e++) w[e] = 0;
  } else {
    const float* p = dist + (size_t)row*1000 + ch*8;
    f32x4 a = *(const f32x4*)p;
    f32x4 b = *(const f32x4*)(p + 4);
#pragma unroll
    for (int e=0;e<4;e++){ w[e] = (short)f2b(a[e]); w[4+e] = (short)f2b(b[e]); }
  }
  *(bf16x8*)&db[(size_t)row*1024 + ch*8] = w;
}

__global__ void k_embed(const float* __restrict__ data, const float* __restrict__ We,
                        const float* __restrict__ be, float* __restrict__ x,
                        unsigned short* __restrict__ xb){
  int idx = blockIdx.x*256 + threadIdx.x;
  int d = idx & 127, bn = idx >> 7;
  float v = data[bn*2]*We[d*2] + data[bn*2+1]*We[d*2+1] + be[d];
  x[idx] = v; xb[idx] = f2b(v);
}

// ---------------- norm-scale reduce: part -> na,nc [32][128] ----------------
__global__ void k_scale(const float* __restrict__ part, int cnt,
                        const float* __restrict__ g, const float* __restrict__ beta,
                        float* __restrict__ na, float* __restrict__ nc){
  int b = blockIdx.x, d = threadIdx.x;   // 32 x 128
  float s1 = 0.f, s2 = 0.f;
  for (int c = 0; c < cnt; ++c){
    size_t pi = (((size_t)b*cnt + c)*128 + d)*2;
    s1 += part[pi]; s2 += part[pi+1];
  }
  float mean = s1 * 1e-3f;
  float var  = s2 * 1e-3f - mean*mean;
  float a = g[d] * rsqrtf(var + 1e-5f);
  na[b*128 + d] = a; nc[b*128 + d] = beta[d] - mean*a;
}

// ---------------- final apply: dout = x*na+nc ----------------
__global__ __launch_bounds__(256) void k_fapply(
  const float* __restrict__ x, const float* __restrict__ na,
  const float* __restrict__ nc, float* __restrict__ dout){
  int blk = blockIdx.x, tid = threadIdx.x;
  int b = blk / 125;
  size_t base = (size_t)blk*1024 + tid*4;
  int d0 = (tid*4) & 127;
  f32x4 v = *(const f32x4*)&x[base];
  f32x4 o;
#pragma unroll
  for (int e=0;e<4;e++) o[e] = v[e]*na[b*128 + d0 + e] + nc[b*128 + d0 + e];
  *(f32x4*)&dout[base] = o;
}

// ---------------- fused QKV GEMM (+inline norm2 of prev layer) ----------------
// grid (512, 2): x = b*16 + t(64 rows), y: 0=Q->sigq, 1=KV->Zc
// LA layout [4 kchunk][64 row][8] — chunk-major, conflict-free both sides
template<int NORM>
__global__ __launch_bounds__(256) void k_qkv(
  const unsigned short* __restrict__ xb, const float* __restrict__ x,
  const float* __restrict__ na2, const float* __restrict__ nc2,
  const unsigned short* __restrict__ Wqb, const unsigned short* __restrict__ Wkb,
  const unsigned short* __restrict__ Wvb,
  unsigned short* __restrict__ sigq, unsigned short* __restrict__ Zc)
{
  __shared__ unsigned short LA[2*2048];          // [buf][4][64][8]
  __shared__ unsigned short LB[2][4][256][8];
  __shared__ float sna[128], snc[128];
  int tid = threadIdx.x, wid = tid>>6, lane = tid&63;
  int l15 = lane&15, lg = lane>>4;
  int wm = wid>>1, wn = wid&1;
  int bt = blockIdx.x, b = bt>>4, t = bt&15;
  int kv = blockIdx.y;
  int lrow = t*64 + lane; if (lrow > 999) lrow = 999;
  size_t arow = (size_t)(b*1000 + lrow);

  if (NORM){
    if (tid < 128){ sna[tid] = na2[b*128 + tid]; snc[tid] = nc2[b*128 + tid]; }
    __syncthreads();
  }

  f32x4 zf = {0.f,0.f,0.f,0.f};
  f32x4 acc[2][4], acc2[2][4];
#pragma unroll
  for (int i=0;i<2;i++)
#pragma unroll
    for (int j=0;j<4;j++){ acc[i][j] = zf; acc2[i][j] = zf; }

  auto stage = [&](int kk, int buf){
    int k0 = kk*32;
    if (NORM){
      // row = lane(tid&63), chunk = wid -> wave writes contiguous 1KB
      const float* p = x + arow*128 + k0 + wid*8;
      f32x4 v0 = *(const f32x4*)p;
      f32x4 v1 = *(const f32x4*)(p + 4);
      bf16x8 w;
#pragma unroll
      for (int e=0;e<4;e++){
        int k = k0 + wid*8;
        w[e]   = (short)f2b(v0[e]*sna[k+e]   + snc[k+e]);
        w[4+e] = (short)f2b(v1[e]*sna[k+4+e] + snc[k+4+e]);
      }
      *(bf16x8*)&LA[buf*2048 + wid*512 + lane*8] = w;
    } else {
      gl16(xb + arow*128 + k0 + wid*8, &LA[buf*2048 + wid*512]);
    }
    if (kv == 0){
#pragma unroll
      for (int t2=0;t2<2;++t2){
        int e = wid + t2*4, g2 = e>>1, nb = e&1;
        gl16(Wqb + (size_t)(nb*64+lane)*128 + k0 + g2*8, &LB[buf][g2][nb*64][0]);
      }
    } else {
#pragma unroll
      for (int t2=0;t2<4;++t2){
        int e = wid + t2*4, g2 = e&3, nb = e>>2;
        const unsigned short* src = (nb < 2)
          ? Wkb + (size_t)(nb*64+lane)*128 + k0 + g2*8
          : Wvb + (size_t)((nb-2)*64+lane)*128 + k0 + g2*8;
        gl16(src, &LB[buf][g2][nb*64][0]);
      }
    }
  };
  auto compute = [&](int buf){
    bf16x8 af[2];
#pragma unroll
    for (int i=0;i<2;i++){
      int row = wm*32 + i*16 + l15;
      af[i] = *(const bf16x8*)&LA[buf*2048 + lg*512 + row*8];
    }
#pragma unroll
    for (int j=0;j<4;j++){
      bf16x8 bq = *(const bf16x8*)&LB[buf][lg][wn*64 + j*16 + l15][0];
#pragma unroll
      for (int i=0;i<2;i++) acc[i][j] = mfma16(af[i], bq, acc[i][j]);
      if (kv){
        bf16x8 bv = *(const bf16x8*)&LB[buf][lg][128 + wn*64 + j*16 + l15][0];
#pragma unroll
        for (int i=0;i<2;i++) acc2[i][j] = mfma16(af[i], bv, acc2[i][j]);
      }
    }
  };

  stage(0, 0);
  __syncthreads();
  for (int kk = 0; kk < 4; ++kk){
    int buf = kk & 1;
    if (kk < 3) stage(kk+1, buf^1);
    compute(buf);
    __syncthreads();
  }

#pragma unroll
  for (int i=0;i<2;i++){
    int m4 = t*64 + wm*32 + i*16 + lg*4;
    if (m4 >= 1000) continue;
#pragma unroll
    for (int j=0;j<4;j++){
      int col = wn*64 + j*16 + l15;
      if (kv == 0){
#pragma unroll
        for (int r=0;r<4;r++)
          sigq[(size_t)(b*1000 + m4 + r)*128 + col] = f2b(1.f/(1.f + __expf(-acc[i][j][r])));
      } else {
        s16x4 pv, pk;
#pragma unroll
        for (int r=0;r<4;r++){
          float ek = __expf(acc[i][j][r]);
          pk[r] = (short)f2b(ek);
          pv[r] = (short)f2b(ek * acc2[i][j][r]);
        }
        size_t base = ((size_t)(b*128 + (m4>>3))*256 + col)*8 + ((m4>>2)&1)*4;
        *(s16x4*)&Zc[base] = pv;
        *(s16x4*)&Zc[base + 1024] = pk;
      }
    }
  }
}

// ---------------- fused attention (+inline norm2) + stats ----------------
// grid (16,32): 64 n x 256 col, K=1024, 4 waves
// A LDS [4 kchunk][64 row][8]: expwrite row=tid&63, chunk=wid -> contiguous 1KB/wave
template<int NORM, int USE16>
__global__ __launch_bounds__(256) void k_attn(
  const float* __restrict__ dist, const unsigned short* __restrict__ db16,
  const unsigned short* __restrict__ Zc, const unsigned short* __restrict__ sigq,
  float* __restrict__ x, float* __restrict__ partA,
  const float* __restrict__ na2, const float* __restrict__ nc2,
  const float* __restrict__ log_scale, const float* __restrict__ alpha, int layer)
{
  union SM {
    struct { unsigned short A[2][4][64][8]; unsigned short B[2][4][256][8]; } st;
    float den[64][128];
  };
  __shared__ SM sm;
  int tid = threadIdx.x, wid = tid>>6, lane = tid&63;
  int l15 = lane&15, lg = lane>>4;
  int bb = blockIdx.y, t = blockIdx.x, n0 = t*64;
  float sc = log_scale[0]*alpha[layer];
  const unsigned short* Zb = Zc + ((size_t)bb << 18);
  int an = n0 + lane; if (an > 999) an = 999;     // row = lane, kchunk = wid
  const size_t drow = (size_t)(bb*1000 + an);

  f32x4 zf = {0.f,0.f,0.f,0.f};
  f32x4 acc[4][4];
#pragma unroll
  for (int i=0;i<4;i++)
#pragma unroll
    for (int j=0;j<4;j++) acc[i][j] = zf;

  auto issueB = [&](int kk, int buf){
#pragma unroll
    for (int t2=0;t2<4;++t2){
      int e = wid + t2*4, g2 = e&3, cb = e>>2;
      gl16(Zb + ((size_t)((kk*4 + g2)*256 + cb*64 + lane))*8, &sm.st.B[buf][g2][cb*64][0]);
    }
  };
  auto loadA = [&](int kk, float* v){
    int k0 = kk*32 + wid*8;
    if (USE16){
      bf16x8 r = *(const bf16x8*)(db16 + drow*1024 + k0);
#pragma unroll
      for (int e=0;e<8;e++) v[e] = b2f((unsigned short)r[e]);
    } else {
      const float* dp = dist + drow*1000;
      if (k0 + 8 <= 1000){
        f32x4 a0 = *(const f32x4*)(dp + k0);
        f32x4 a1 = *(const f32x4*)(dp + k0 + 4);
#pragma unroll
        for (int e=0;e<4;e++){ v[e] = a0[e]; v[4+e] = a1[e]; }
      } else {
#pragma unroll
        for (int e=0;e<8;e++){
          int m = k0 + e; if (m > 999) m = 999;
          v[e] = dp[m];
        }
      }
    }
  };
  auto expwrite = [&](const float* v, int buf){
    bf16x8 w;
#pragma unroll
    for (int e=0;e<8;e++) w[e] = (short)f2b(__expf(sc*v[e]));
    *(bf16x8*)&sm.st.A[buf][wid][lane][0] = w;   // contiguous 1KB per wave
  };
  auto compute = [&](int buf){
    bf16x8 af[4], bq[4];
#pragma unroll
    for (int i=0;i<4;i++) af[i] = *(const bf16x8*)&sm.st.A[buf][lg][i*16 + l15][0];
#pragma unroll
    for (int j=0;j<4;j++) bq[j] = *(const bf16x8*)&sm.st.B[buf][lg][wid*64 + j*16 + l15][0];
#pragma unroll
    for (int i=0;i<4;i++)
#pragma unroll
      for (int j=0;j<4;j++)
        acc[i][j] = mfma16(af[i], bq[j], acc[i][j]);
  };

  float av[8];
  issueB(0, 0);
  loadA(0, av);
  expwrite(av, 0);
  __syncthreads();
  for (int kk = 0; kk < 32; ++kk){
    int buf = kk & 1;
    float nv[8];
    if (kk < 31){ issueB(kk+1, buf^1); loadA(kk+1, nv); }
    compute(buf);
    if (kk < 31) expwrite(nv, buf^1);
    __syncthreads();
  }

  if (wid >= 2){
#pragma unroll
    for (int i=0;i<4;i++)
#pragma unroll
      for (int j=0;j<4;j++){
        int dcol = (wid-2)*64 + j*16 + l15;
#pragma unroll
        for (int r=0;r<4;r++)
          sm.den[i*16 + lg*4 + r][dcol] = acc[i][j][r];
      }
  }
  __syncthreads();
  if (wid < 2){
    float nav[4], ncv[4];
    if (NORM){
#pragma unroll
      for (int j=0;j<4;j++){
        int d = wid*64 + j*16 + l15;
        nav[j] = na2[bb*128 + d]; ncv[j] = nc2[bb*128 + d];
      }
    }
    float s1[4] = {0.f,0.f,0.f,0.f}, s2[4] = {0.f,0.f,0.f,0.f};
#pragma unroll
    for (int i=0;i<4;i++){
#pragma unroll
      for (int r=0;r<4;r++){
        int n = n0 + i*16 + lg*4 + r;
        if (n < 1000){
          size_t rowi = ((size_t)bb*1000 + n)*128;
#pragma unroll
          for (int j=0;j<4;j++){
            int d = wid*64 + j*16 + l15;
            float xv = x[rowi + d];
            if (NORM) xv = xv*nav[j] + ncv[j];
            float y = xv + b2f(sigq[rowi + d]) * acc[i][j][r] / sm.den[i*16 + lg*4 + r][d];
            x[rowi + d] = y;
            s1[j] += y; s2[j] += y*y;
          }
        }
      }
    }
#pragma unroll
    for (int j=0;j<4;j++){
      s1[j] += __shfl_xor(s1[j], 16); s2[j] += __shfl_xor(s2[j], 16);
      s1[j] += __shfl_xor(s1[j], 32); s2[j] += __shfl_xor(s2[j], 32);
    }
    if (lg == 0){
#pragma unroll
      for (int j=0;j<4;j++){
        int d = wid*64 + j*16 + l15;
        size_t pi = (((size_t)bb*16 + t)*128 + d)*2;
        partA[pi] = s1[j]; partA[pi+1] = s2[j];
      }
    }
  }
}

// ---------------- FF1 + fused norm1 ----------------
// grid 512, 512 thr, BN=512, K=128; side out: x1 = inorm1(x) f32
// LA [4 kchunk][64 row][8]: stage row=tid&63, chunk=(tid>>6)
__global__ __launch_bounds__(512) void k_ff1(
  const float* __restrict__ x, const float* __restrict__ partA,
  const float* __restrict__ g1, const float* __restrict__ b1,
  const unsigned short* __restrict__ W1b, const float* __restrict__ bw1,
  float* __restrict__ x1, unsigned short* __restrict__ h1)
{
  __shared__ unsigned short LA[2][4][64][8];
  __shared__ unsigned short LB[2][4][512][8];
  __shared__ float sna[128], snc[128];
  int tid = threadIdx.x, wid = tid>>6, lane = tid&63;
  int l15 = lane&15, lg = lane>>4;
  int wm = wid>>2, wn = wid&3;
  int bt = blockIdx.x, b = bt>>4, t = bt&15;

  if (tid < 128){
    float s1 = 0.f, s2 = 0.f;
    for (int c = 0; c < 16; ++c){
      size_t pi = (((size_t)b*16 + c)*128 + tid)*2;
      s1 += partA[pi]; s2 += partA[pi+1];
    }
    float mean = s1 * 1e-3f;
    float var  = s2 * 1e-3f - mean*mean;
    float a = g1[tid] * rsqrtf(var + 1e-5f);
    sna[tid] = a; snc[tid] = b1[tid] - mean*a;
  }
  __syncthreads();

  f32x4 zf = {0.f,0.f,0.f,0.f};
  f32x4 acc[2][8];
#pragma unroll
  for (int i=0;i<2;i++)
#pragma unroll
    for (int j=0;j<8;j++) acc[i][j] = zf;

  auto stage = [&](int kk, int buf){
    int k0 = kk*32;
    if (tid < 256){
      int row = tid & 63, g2 = tid >> 6;      // chunk-major, conflict-free
      int lr = t*64 + row;
      int rr = lr > 999 ? 999 : lr;
      const float* p = x + ((size_t)(b*1000 + rr))*128 + k0 + g2*8;
      f32x4 v0 = *(const f32x4*)p;
      f32x4 v1 = *(const f32x4*)(p + 4);
      f32x4 o0, o1;
      bf16x8 w;
#pragma unroll
      for (int e=0;e<4;e++){
        int k = k0 + g2*8;
        o0[e] = v0[e]*sna[k+e]   + snc[k+e];
        o1[e] = v1[e]*sna[k+4+e] + snc[k+4+e];
        w[e]   = (short)f2b(o0[e]);
        w[4+e] = (short)f2b(o1[e]);
      }
      *(bf16x8*)&LA[buf][g2][row][0] = w;
      if (lr < 1000){
        float* q = x1 + ((size_t)(b*1000 + lr))*128 + k0 + g2*8;
        *(f32x4*)q = o0; *(f32x4*)(q+4) = o1;
      }
    }
#pragma unroll
    for (int t2=0;t2<4;++t2){
      int e = wid*4 + t2;           // wave-uniform
      int g2 = e & 3, nb = e >> 2;
      gl16(W1b + (size_t)(nb*64 + lane)*128 + k0 + g2*8, &LB[buf][g2][nb*64][0]);
    }
  };
  auto compute = [&](int buf){
    bf16x8 af[2];
#pragma unroll
    for (int i=0;i<2;i++) af[i] = *(const bf16x8*)&LA[buf][lg][wm*32 + i*16 + l15][0];
#pragma unroll
    for (int j=0;j<8;j++){
      bf16x8 bq = *(const bf16x8*)&LB[buf][lg][wn*128 + j*16 + l15][0];
#pragma unroll
      for (int i=0;i<2;i++) acc[i][j] = mfma16(af[i], bq, acc[i][j]);
    }
  };

  stage(0, 0);
  __syncthreads();
  for (int kk = 0; kk < 4; ++kk){
    int buf = kk & 1;
    if (kk < 3) stage(kk+1, buf^1);
    compute(buf);
    __syncthreads();
  }

#pragma unroll
  for (int i=0;i<2;i++){
    int m4 = t*64 + wm*32 + i*16 + lg*4;
    if (m4 >= 1000) continue;
#pragma unroll
    for (int j=0;j<8;j++){
      int col = wn*128 + j*16 + l15;
      float bz = bw1[col];
#pragma unroll
      for (int r=0;r<4;r++){
        float v = acc[i][j][r] + bz;
        h1[(size_t)(b*1000 + m4 + r)*512 + col] = f2b(v > 0.f ? v : 0.f);
      }
    }
  }
}

// ---------------- FF2 + residual(f32) + stats ----------------
// grid 512, K=512
__global__ __launch_bounds__(256) void k_ff2(
  const unsigned short* __restrict__ h1, const unsigned short* __restrict__ W2b,
  const float* __restrict__ bw2, const float* __restrict__ x1,
  float* __restrict__ x, float* __restrict__ partF)
{
  __shared__ unsigned short LA[2][4][64][8];
  __shared__ unsigned short LB[2][4][128][8];
  int tid = threadIdx.x, wid = tid>>6, lane = tid&63;
  int l15 = lane&15, lg = lane>>4;
  int wm = wid>>1, wn = wid&1;
  int bt = blockIdx.x, b = bt>>4, t = bt&15;
  int lrow = t*64 + lane; if (lrow > 999) lrow = 999;
  size_t arow = (size_t)(b*1000 + lrow);

  f32x4 zf = {0.f,0.f,0.f,0.f};
  f32x4 acc[2][4];
#pragma unroll
  for (int i=0;i<2;i++)
#pragma unroll
    for (int j=0;j<4;j++) acc[i][j] = zf;

  auto stage = [&](int kk, int buf){
    int k0 = kk*32;
    gl16(h1 + arow*512 + k0 + wid*8, &LA[buf][wid][0][0]);
#pragma unroll
    for (int t2=0;t2<2;++t2){
      int e = wid + t2*4, g2 = e>>1, nb = e&1;
      gl16(W2b + (size_t)(nb*64 + lane)*512 + k0 + g2*8, &LB[buf][g2][nb*64][0]);
    }
  };
  auto compute = [&](int buf){
    bf16x8 af[2];
#pragma unroll
    for (int i=0;i<2;i++) af[i] = *(const bf16x8*)&LA[buf][lg][wm*32 + i*16 + l15][0];
#pragma unroll
    for (int j=0;j<4;j++){
      bf16x8 bq = *(const bf16x8*)&LB[buf][lg][wn*64 + j*16 + l15][0];
#pragma unroll
      for (int i=0;i<2;i++) acc[i][j] = mfma16(af[i], bq, acc[i][j]);
    }
  };

  stage(0, 0);
  __syncthreads();
  for (int kk = 0; kk < 16; ++kk){
    int buf = kk & 1;
    if (kk < 15) stage(kk+1, buf^1);
    compute(buf);
    __syncthreads();
  }

  float s1[4] = {0.f,0.f,0.f,0.f}, s2[4] = {0.f,0.f,0.f,0.f};
#pragma unroll
  for (int i=0;i<2;i++){
    int m4 = t*64 + wm*32 + i*16 + lg*4;
    if (m4 >= 1000) continue;
#pragma unroll
    for (int j=0;j<4;j++){
      int col = wn*64 + j*16 + l15;
      float bz = bw2[col];
#pragma unroll
      for (int r=0;r<4;r++){
        size_t idx = (size_t)(b*1000 + m4 + r)*128 + col;
        float y = acc[i][j][r] + bz + x1[idx];
        x[idx] = y;
        s1[j] += y; s2[j] += y*y;
      }
    }
  }
#pragma unroll
  for (int j=0;j<4;j++){
    s1[j] += __shfl_xor(s1[j], 16); s2[j] += __shfl_xor(s2[j], 16);
    s1[j] += __shfl_xor(s1[j], 32); s2[j] += __shfl_xor(s2[j], 32);
  }
  if (lg == 0){
#pragma unroll
    for (int j=0;j<4;j++){
      int d = wn*64 + j*16 + l15;
      size_t pi = (((size_t)b*32 + t*2 + wm)*128 + d)*2;
      partF[pi] = s1[j]; partF[pi+1] = s2[j];
    }
  }
}

extern "C" void kernel_launch(void* const* d_in, const int* in_sizes, int n_in,
                              void* d_out, int out_size, void* d_ws, size_t ws_size,
                              hipStream_t stream) {
  const float* data = (const float*)d_in[0];
  const float* dist = (const float*)d_in[1];
  const float* log_scale = (const float*)d_in[2];
  const float* We = (const float*)d_in[3];
  const float* be = (const float*)d_in[4];
  const float* Wq = (const float*)d_in[5];
  const float* Wk = (const float*)d_in[6];
  const float* Wv = (const float*)d_in[7];
  const float* g1 = (const float*)d_in[8];
  const float* b1 = (const float*)d_in[9];
  const float* W1 = (const float*)d_in[10];
  const float* bw1 = (const float*)d_in[11];
  const float* W2 = (const float*)d_in[12];
  const float* bw2 = (const float*)d_in[13];
  const float* g2 = (const float*)d_in[14];
  const float* b2 = (const float*)d_in[15];
  const float* alpha = (const float*)d_in[16];
  float* dout = (float*)d_out;

  char* ws = (char*)d_ws;
  size_t off = 0;
  auto alloc = [&](size_t bytes) -> void* {
    void* p = ws + off; off += (bytes + 255) & ~(size_t)255; return p;
  };
  unsigned short* xb  = (unsigned short*)alloc(8192000);    // [32000][128] bf16
  float* x            = (float*)alloc(16384000);            // [32000][128] f32
  unsigned short* sigq= (unsigned short*)alloc(8192000);    // [32000][128] bf16
  unsigned short* Zc  = (unsigned short*)alloc(16777216);   // [32][128][256][8] bf16
  unsigned short* h1  = (unsigned short*)alloc(32768000);   // [32000][512] bf16
  float* x1           = (float*)alloc(16384000);            // [32000][128] f32
  float* partA        = (float*)alloc(524288);              // [32][16][128][2]
  float* partF        = (float*)alloc(1048576);             // [32][32][128][2]
  float* na2          = (float*)alloc(16384);
  float* nc2          = (float*)alloc(16384);
  unsigned short* wqb = (unsigned short*)alloc(196608);
  unsigned short* wkb = (unsigned short*)alloc(196608);
  unsigned short* wvb = (unsigned short*)alloc(196608);
  unsigned short* w1b = (unsigned short*)alloc(786432);
  unsigned short* w2b = (unsigned short*)alloc(786432);
  if (off > ws_size) return;
  unsigned short* db16p = nullptr;
  if (ws_size >= off + 131072256) db16p = (unsigned short*)alloc(131072000); // [32000][1024] bf16

  hipMemsetAsync(Zc, 0, 16777216, stream);
  k_cvt5<<<4224, 256, 0, stream>>>(Wq, Wk, Wv, W1, W2, wqb, wkb, wvb, w1b, w2b);
  if (db16p) k_cvtdist<<<16000, 256, 0, stream>>>(dist, db16p);
  k_embed<<<16000, 256, 0, stream>>>(data, We, be, x, xb);

  for (int i = 0; i < LCOUNT; ++i){
    if (i > 0)
      k_scale<<<32, 128, 0, stream>>>(partF, 32, g2 + (i-1)*128, b2 + (i-1)*128, na2, nc2);
    if (i == 0)
      k_qkv<0><<<dim3(512,2), 256, 0, stream>>>(xb, x, nullptr, nullptr,
                                                wqb + i*16384, wkb + i*16384, wvb + i*16384,
                                                sigq, Zc);
    else
      k_qkv<1><<<dim3(512,2), 256, 0, stream>>>(nullptr, x, na2, nc2,
                                                wqb + i*16384, wkb + i*16384, wvb + i*16384,
                                                sigq, Zc);
    if (i == 0){
      if (db16p) k_attn<0,1><<<dim3(16,32), 256, 0, stream>>>(dist, db16p, Zc, sigq, x, partA,
                                                              nullptr, nullptr, log_scale, alpha, i);
      else       k_attn<0,0><<<dim3(16,32), 256, 0, stream>>>(dist, nullptr, Zc, sigq, x, partA,
                                                              nullptr, nullptr, log_scale, alpha, i);
    } else {
      if (db16p) k_attn<1,1><<<dim3(16,32), 256, 0, stream>>>(dist, db16p, Zc, sigq, x, partA,
                                                              na2, nc2, log_scale, alpha, i);
      else       k_attn<1,0><<<dim3(16,32), 256, 0, stream>>>(dist, nullptr, Zc, sigq, x, partA,
                                                              na2, nc2, log_scale, alpha, i);
    }
    k_ff1<<<512, 512, 0, stream>>>(x, partA, g1 + i*128, b1 + i*128,
                                   w1b + i*65536, bw1 + i*512, x1, h1);
    k_ff2<<<512, 256, 0, stream>>>(h1, w2b + i*65536, bw2 + i*128, x1, x, partF);
  }
  k_scale<<<32, 128, 0, stream>>>(partF, 32, g2 + 5*128, b2 + 5*128, na2, nc2);
  k_fapply<<<4000, 256, 0, stream>>>(x, na2, nc2, dout);
}